// Round 2
// baseline (590.435 us; speedup 1.0000x reference)
//
#include <hip/hip_runtime.h>
#include <math.h>

// ---------------- sizes ----------------
#define Bn 8
#define Wn 20
#define Mn 512
#define Fn 16
#define Hn 128
#define HALFn 64
#define Kn 10
#define NSEQ (Bn*Mn)          // 4096

__device__ __forceinline__ float sigmoidf_(float x) {
  return 1.0f / (1.0f + __expf(-x));
}
__device__ __forceinline__ float tanhf_(float x) {
  float xx = fminf(fmaxf(x, -15.f), 15.f);
  float e = __expf(2.f * xx);
  return (e - 1.f) / (e + 1.f);
}
__device__ __forceinline__ float reluf_(float x) { return fmaxf(x, 0.f); }

// ---------------- prep: transpose Whh (384,128) -> WhhT (128,384) ----------------
__global__ __launch_bounds__(256) void whht_kernel(const float* __restrict__ Whh,
                                                   float* __restrict__ WhhT) {
  int idx = blockIdx.x * 256 + threadIdx.x;
  if (idx < 384 * 128) {
    int g = idx >> 7, k = idx & 127;
    WhhT[k * 384 + g] = Whh[idx];
  }
}

// ---------------- GRU: 8 seqs/block, 384 threads, weights in registers ----------------
// w[128] (Whh row) in VGPRs loaded once; Wih in padded LDS; x double-buffered;
// 2 barriers per timestep. Target <=170 VGPR -> 3 waves/SIMD (2 blocks/CU).
__global__ __launch_bounds__(384, 3) void gru_kernel(
    const float* __restrict__ X, const float* __restrict__ WhhT,
    const float* __restrict__ Wih, const float* __restrict__ bih,
    const float* __restrict__ bhh, float* __restrict__ last_hid) {
  const int g = threadIdx.x;          // 0..383
  const int gate = g >> 7;            // 0=r,1=z,2=n
  const int j = g & 127;
  const int n0 = blockIdx.x * 8;
  const int b = n0 >> 9;
  const int m0 = n0 & 511;

  __shared__ float h_s[8][128];
  __shared__ float r_s[8][128];
  __shared__ float z_s[8][128];
  __shared__ float xt_T[2][16][12];   // [buf][f][s], row stride 12 floats (16B-aligned)
  __shared__ float wih_s[384 * 17];   // padded stride 17: conflict-free lane reads

  // ---- one-time: Whh row into registers (coalesced via WhhT) ----
  float w[128];
#pragma unroll
  for (int k = 0; k < 128; ++k) w[k] = WhhT[k * 384 + g];

  // ---- one-time: Wih into LDS ----
  for (int idx = g; idx < 384 * 16; idx += 384) {
    int gg = idx >> 4, f = idx & 15;
    wih_s[gg * 17 + f] = Wih[idx];
  }
  const float xb = bih[g];
  const float hb = bhh[g];

  const float* Xbase = X + ((long)b * Wn * Mn + m0) * Fn;
  if (g < 128) {
#pragma unroll
    for (int s = 0; s < 8; ++s) h_s[s][j] = 0.f;
    float xv = Xbase[g];              // t=0 tile: s=g>>4, f=g&15
    xt_T[0][g & 15][g >> 4] = xv;
  }
  __syncthreads();

  for (int t = 0; t < 20; ++t) {
    const int cur = t & 1, nxt = cur ^ 1;
    // prefetch next x tile (hidden under the matmul)
    float xnext = 0.f;
    if (g < 128) {
      int tt = (t < 19) ? (t + 1) : 19;
      xnext = Xbase[(long)tt * (Mn * Fn) + g];
    }

    // ---- phase 1: acc[s] = Whh[g,:] . h[s,:]  (LDS broadcast reads) ----
    float acc[8] = {0, 0, 0, 0, 0, 0, 0, 0};
#pragma unroll
    for (int k4 = 0; k4 < 128; k4 += 4) {
#pragma unroll
      for (int s = 0; s < 8; ++s) {
        float4 h4 = *(const float4*)&h_s[s][k4];
        acc[s] = fmaf(h4.x, w[k4 + 0], acc[s]);
        acc[s] = fmaf(h4.y, w[k4 + 1], acc[s]);
        acc[s] = fmaf(h4.z, w[k4 + 2], acc[s]);
        acc[s] = fmaf(h4.w, w[k4 + 3], acc[s]);
      }
    }

    // ---- phase 2: gq[s] = Wih[g,:] . x_t[s,:] + bih[g] ----
    float gq[8];
#pragma unroll
    for (int s = 0; s < 8; ++s) gq[s] = xb;
#pragma unroll
    for (int f = 0; f < 16; ++f) {
      float wf = wih_s[g * 17 + f];
      float4 xa = *(const float4*)&xt_T[cur][f][0];
      float4 xc = *(const float4*)&xt_T[cur][f][4];
      gq[0] = fmaf(xa.x, wf, gq[0]);
      gq[1] = fmaf(xa.y, wf, gq[1]);
      gq[2] = fmaf(xa.z, wf, gq[2]);
      gq[3] = fmaf(xa.w, wf, gq[3]);
      gq[4] = fmaf(xc.x, wf, gq[4]);
      gq[5] = fmaf(xc.y, wf, gq[5]);
      gq[6] = fmaf(xc.z, wf, gq[6]);
      gq[7] = fmaf(xc.w, wf, gq[7]);
    }

    if (gate == 0) {
#pragma unroll
      for (int s = 0; s < 8; ++s) r_s[s][j] = sigmoidf_(gq[s] + acc[s] + hb);
    } else if (gate == 1) {
#pragma unroll
      for (int s = 0; s < 8; ++s) z_s[s][j] = sigmoidf_(gq[s] + acc[s] + hb);
    }
    if (g < 128) xt_T[nxt][g & 15][g >> 4] = xnext;
    __syncthreads();  // r,z,x(t+1) ready; all h reads done

    if (gate == 2) {
#pragma unroll
      for (int s = 0; s < 8; ++s) {
        float n = tanhf_(gq[s] + r_s[s][j] * (acc[s] + hb));
        float z = z_s[s][j];
        h_s[s][j] = (1.f - z) * n + z * h_s[s][j];
      }
    }
    __syncthreads();  // h updated
  }
  if (g < 128) {
#pragma unroll
    for (int s = 0; s < 8; ++s) last_hid[(long)(n0 + s) * Hn + j] = h_s[s][j];
  }
}

// ---------------- p1/p2: per-row projections (4 rows/block) ----------------
__global__ __launch_bounds__(128) void attn_p_kernel(
    const float* __restrict__ last_hid, const float* __restrict__ W1,
    const float* __restrict__ W2, const float* __restrict__ b1,
    float* __restrict__ p1, float* __restrict__ p2) {
  int r0 = blockIdx.x * 4;
  int t = threadIdx.x;
  __shared__ float hs[4][128];
  for (int idx = t; idx < 512; idx += 128)
    hs[idx >> 7][idx & 127] = last_hid[(long)r0 * 128 + idx];
  __syncthreads();
  int k = t & 63;
  const float* Wp = (t < 64) ? W1 : W2;
  float a0, a1, a2, a3;
  a0 = a1 = a2 = a3 = (t < 64) ? b1[k] : 0.f;
  for (int h = 0; h < 128; h += 4) {
    float4 w = *(const float4*)&Wp[k * 128 + h];
    float4 q0 = *(const float4*)&hs[0][h];
    float4 q1 = *(const float4*)&hs[1][h];
    float4 q2 = *(const float4*)&hs[2][h];
    float4 q3 = *(const float4*)&hs[3][h];
    a0 += q0.x * w.x + q0.y * w.y + q0.z * w.z + q0.w * w.w;
    a1 += q1.x * w.x + q1.y * w.y + q1.z * w.z + q1.w * w.w;
    a2 += q2.x * w.x + q2.y * w.y + q2.z * w.z + q2.w * w.w;
    a3 += q3.x * w.x + q3.y * w.y + q3.z * w.z + q3.w * w.w;
  }
  float* outp = (t < 64) ? p1 : p2;
  outp[(r0 + 0) * 64 + k] = a0;
  outp[(r0 + 1) * 64 + k] = a1;
  outp[(r0 + 2) * 64 + k] = a2;
  outp[(r0 + 3) * 64 + k] = a3;
}

// ---------------- a_mx (raw): 16x16 tile per block ----------------
__global__ __launch_bounds__(256) void amx_kernel(
    const float* __restrict__ p1, const float* __restrict__ p2,
    const float* __restrict__ V, const float* __restrict__ bv,
    float* __restrict__ amx) {
  int tid = threadIdx.x;
  int j0 = blockIdx.x * 16, i0 = blockIdx.y * 16, bz = blockIdx.z;
  __shared__ float p1s[16][68];
  __shared__ float p2s[16][68];
  __shared__ float Vs[64];
  if (tid < 64) Vs[tid] = V[tid];
#pragma unroll
  for (int l = 0; l < 4; ++l) {
    int idx = l * 256 + tid;
    int rr = idx >> 6, k = idx & 63;
    p1s[rr][k] = p1[(long)(bz * 512 + j0 + rr) * 64 + k];
    p2s[rr][k] = p2[(long)(bz * 512 + i0 + rr) * 64 + k];
  }
  __syncthreads();
  int ii = tid >> 4, jj = tid & 15;
  float acc = 0.f;
#pragma unroll 4
  for (int k = 0; k < 64; ++k) {
    float pre = p1s[jj][k] + p2s[ii][k];
    float e = (pre > 0.f) ? pre : (__expf(pre) - 1.f);
    acc = fmaf(e, Vs[k], acc);
  }
  amx[((long)bz * 512 + i0 + ii) * 512 + j0 + jj] = acc + bv[0];
}

// ---------------- column L2 norm over i (dim=1) -> reciprocal scale ----------------
__global__ __launch_bounds__(256) void colnorm_kernel(const float* __restrict__ amx,
                                                      float* __restrict__ scale) {
  int b = blockIdx.y;
  int j0 = blockIdx.x * 32;
  int jl = threadIdx.x & 31, ip = threadIdx.x >> 5;
  const float* base = amx + (long)b * 512 * 512;
  float ss = 0.f;
  for (int i = ip; i < 512; i += 8) {
    float v = base[(long)i * 512 + j0 + jl];
    ss = fmaf(v, v, ss);
  }
  __shared__ float red[8][33];
  red[ip][jl] = ss;
  __syncthreads();
  if (threadIdx.x < 32) {
    float s = 0.f;
#pragma unroll
    for (int p = 0; p < 8; ++p) s += red[p][threadIdx.x];
    scale[b * 512 + j0 + threadIdx.x] = 1.f / fmaxf(sqrtf(s), 1e-12f);
  }
}

// ---------------- per-node convs -> r_l (b,m,30) ----------------
__global__ __launch_bounds__(128) void conv_kernel(
    const float* __restrict__ X, const float* __restrict__ conv_w,
    const float* __restrict__ conv_b, const float* __restrict__ convl_w,
    const float* __restrict__ convl_b, float* __restrict__ r_l) {
  int tid = threadIdx.x;
  int n0 = blockIdx.x * 8;
  int b = n0 >> 9, m0 = n0 & 511;
  __shared__ float xs[8][16][20];
  __shared__ float cw[3200];
  __shared__ float clw[1600];
  for (int idx = tid; idx < 3200; idx += 128) cw[idx] = conv_w[idx];
  for (int idx = tid; idx < 1600; idx += 128) clw[idx] = convl_w[idx];
  for (int w = 0; w < 20; ++w)
    xs[tid >> 4][tid & 15][w] = X[((long)(b * 20 + w) * 512 + m0) * 16 + tid];
  __syncthreads();
  if (tid < 80) {
    int s = tid / 10, k = tid % 10;
    float a0 = conv_b[k];
    float l0 = convl_b[k], l1 = convl_b[k];
    for (int f = 0; f < 16; ++f) {
#pragma unroll
      for (int w = 0; w < 20; ++w) a0 = fmaf(xs[s][f][w], cw[k * 320 + f * 20 + w], a0);
#pragma unroll
      for (int q = 0; q < 10; ++q) {
        float wv = clw[k * 160 + f * 10 + q];
        l0 = fmaf(xs[s][f][2 * q], wv, l0);
        l1 = fmaf(xs[s][f][2 * q + 1], wv, l1);
      }
    }
    long base = (long)(n0 + s) * 30 + k * 3;
    r_l[base + 0] = reluf_(a0);
    r_l[base + 1] = reluf_(l0);
    r_l[base + 2] = reluf_(l1);
  }
}

// ---------------- t1 = r_l @ gc1_W  (4 rows/block) ----------------
__global__ __launch_bounds__(128) void t1_kernel(const float* __restrict__ r_l,
                                                 const float* __restrict__ gc1_W,
                                                 float* __restrict__ t1) {
  int r0 = blockIdx.x * 4;
  int h = threadIdx.x;
  __shared__ float rs[4][30];
  if (h < 120) rs[h / 30][h % 30] = r_l[(long)r0 * 30 + h];
  __syncthreads();
  float a0 = 0, a1 = 0, a2 = 0, a3 = 0;
#pragma unroll
  for (int q = 0; q < 30; ++q) {
    float w = gc1_W[q * 128 + h];
    a0 = fmaf(rs[0][q], w, a0);
    a1 = fmaf(rs[1][q], w, a1);
    a2 = fmaf(rs[2][q], w, a2);
    a3 = fmaf(rs[3][q], w, a3);
  }
  t1[(long)(r0 + 0) * 128 + h] = a0;
  t1[(long)(r0 + 1) * 128 + h] = a1;
  t1[(long)(r0 + 2) * 128 + h] = a2;
  t1[(long)(r0 + 3) * 128 + h] = a3;
}

// ---- gemm: c = sigmoid((amx*scl)@Wb + wb); A = adj*c + (amx*scl)*(1-c) ----
// column scaling fused (scale_kernel removed)
__global__ __launch_bounds__(256) void gemm_cA(
    const float* __restrict__ amx, const float* __restrict__ Wb,
    const float* __restrict__ adj, const float* __restrict__ wb,
    const float* __restrict__ scl, float* __restrict__ A) {
  const int bz = blockIdx.z;
  const int i0 = blockIdx.y * 64;
  const int j0 = blockIdx.x * 64;
  const int tid = threadIdx.x;
  const int ti = tid >> 4, tj = tid & 15;
  __shared__ float As[16][64];
  __shared__ float Bs[16][64];
  float acc[4][4] = {};
  const float* Abase = amx + (long)bz * 512 * 512;
  const float* sbase = scl + bz * 512;
  for (int kk0 = 0; kk0 < 512; kk0 += 16) {
    __syncthreads();
    {
      int il = tid >> 2, kq = (tid & 3) * 4;
      float4 v = *(const float4*)&Abase[(long)(i0 + il) * 512 + kk0 + kq];
      float4 sc = *(const float4*)&sbase[kk0 + kq];
      As[kq + 0][il] = v.x * sc.x; As[kq + 1][il] = v.y * sc.y;
      As[kq + 2][il] = v.z * sc.z; As[kq + 3][il] = v.w * sc.w;
      int kk = tid >> 4, jl = (tid & 15) * 4;
      *(float4*)&Bs[kk][jl] = *(const float4*)&Wb[(long)(kk0 + kk) * 512 + j0 + jl];
    }
    __syncthreads();
#pragma unroll
    for (int k = 0; k < 16; ++k) {
      float4 a4 = *(const float4*)&As[k][ti * 4];
      float4 b4 = *(const float4*)&Bs[k][tj * 4];
      float av[4] = {a4.x, a4.y, a4.z, a4.w};
      float bw[4] = {b4.x, b4.y, b4.z, b4.w};
#pragma unroll
      for (int a = 0; a < 4; ++a)
#pragma unroll
        for (int c = 0; c < 4; ++c) acc[a][c] = fmaf(av[a], bw[c], acc[a][c]);
    }
  }
  const float wbv = wb[0];
  float4 sj = *(const float4*)&sbase[j0 + tj * 4];
#pragma unroll
  for (int a = 0; a < 4; ++a) {
    int i = i0 + ti * 4 + a;
    long idx4 = (long)bz * 512 * 512 + (long)i * 512 + j0 + tj * 4;
    float4 am = *(const float4*)&amx[idx4];
    am.x *= sj.x; am.y *= sj.y; am.z *= sj.z; am.w *= sj.w;
    float4 ad = *(const float4*)&adj[(long)i * 512 + j0 + tj * 4];
    float4 o;
    float c0 = sigmoidf_(acc[a][0] + wbv);
    float c1 = sigmoidf_(acc[a][1] + wbv);
    float c2 = sigmoidf_(acc[a][2] + wbv);
    float c3 = sigmoidf_(acc[a][3] + wbv);
    o.x = ad.x * c0 + am.x * (1.f - c0);
    o.y = ad.y * c1 + am.y * (1.f - c1);
    o.z = ad.z * c2 + am.z * (1.f - c2);
    o.w = ad.w * c3 + am.w * (1.f - c3);
    *(float4*)&A[idx4] = o;
  }
}

// ---------------- gemm: h1 = relu(A @ t1 + gc1_b) ----------------
__global__ __launch_bounds__(256) void gemm_h1(
    const float* __restrict__ A, const float* __restrict__ t1,
    const float* __restrict__ gc1_b, float* __restrict__ h1) {
  const int bz = blockIdx.z;
  const int i0 = blockIdx.y * 64;
  const int j0 = blockIdx.x * 64;   // within 128
  const int tid = threadIdx.x;
  const int ti = tid >> 4, tj = tid & 15;
  __shared__ float As[16][64];
  __shared__ float Bs[16][64];
  float acc[4][4] = {};
  const float* Abase = A + (long)bz * 512 * 512;
  const float* Bbase = t1 + (long)bz * 512 * 128;
  for (int kk0 = 0; kk0 < 512; kk0 += 16) {
    __syncthreads();
    {
      int il = tid >> 2, kq = (tid & 3) * 4;
      float4 v = *(const float4*)&Abase[(long)(i0 + il) * 512 + kk0 + kq];
      As[kq + 0][il] = v.x; As[kq + 1][il] = v.y;
      As[kq + 2][il] = v.z; As[kq + 3][il] = v.w;
      int kk = tid >> 4, jl = (tid & 15) * 4;
      *(float4*)&Bs[kk][jl] = *(const float4*)&Bbase[(long)(kk0 + kk) * 128 + j0 + jl];
    }
    __syncthreads();
#pragma unroll
    for (int k = 0; k < 16; ++k) {
      float4 a4 = *(const float4*)&As[k][ti * 4];
      float4 b4 = *(const float4*)&Bs[k][tj * 4];
      float av[4] = {a4.x, a4.y, a4.z, a4.w};
      float bw[4] = {b4.x, b4.y, b4.z, b4.w};
#pragma unroll
      for (int a = 0; a < 4; ++a)
#pragma unroll
        for (int c = 0; c < 4; ++c) acc[a][c] = fmaf(av[a], bw[c], acc[a][c]);
    }
  }
#pragma unroll
  for (int a = 0; a < 4; ++a) {
    int i = i0 + ti * 4 + a;
    int jj = j0 + tj * 4;
    float4 o;
    o.x = reluf_(acc[a][0] + gc1_b[jj + 0]);
    o.y = reluf_(acc[a][1] + gc1_b[jj + 1]);
    o.z = reluf_(acc[a][2] + gc1_b[jj + 2]);
    o.w = reluf_(acc[a][3] + gc1_b[jj + 3]);
    *(float4*)&h1[((long)bz * 512 + i) * 128 + jj] = o;
  }
}

// ---------------- t2 = h1 @ gc2_W (16 rows/block) ----------------
__global__ __launch_bounds__(256) void t2_kernel(const float* __restrict__ h1,
                                                 const float* __restrict__ gc2_W,
                                                 float* __restrict__ t2) {
  int tid = threadIdx.x;
  int r0 = blockIdx.x * 16;
  __shared__ float hs[16 * 129];
  __shared__ float wsh[1280];
  for (int idx = tid; idx < 2048; idx += 256) {
    int r = idx >> 7, k = idx & 127;
    hs[r * 129 + k] = h1[(long)(r0 + r) * 128 + k];
  }
  for (int idx = tid; idx < 1280; idx += 256) wsh[idx] = gc2_W[idx];
  __syncthreads();
  if (tid < 160) {
    int r = tid / 10, c = tid % 10;
    float a = 0.f;
#pragma unroll 4
    for (int k = 0; k < 128; ++k) a = fmaf(hs[r * 129 + k], wsh[k * 10 + c], a);
    t2[(long)(r0 + r) * 10 + c] = a;
  }
}

// ---------------- out_spatial = relu(A @ t2 + gc2_b) ----------------
__global__ __launch_bounds__(256) void spat_kernel(
    const float* __restrict__ A, const float* __restrict__ t2,
    const float* __restrict__ gc2_b, float* __restrict__ osp) {
  int tid = threadIdx.x;
  int bz = blockIdx.y;
  int i0 = blockIdx.x * 64;
  __shared__ float t2s[5120];
  __shared__ float As[64 * 33];
  for (int idx = tid; idx < 5120; idx += 256) t2s[idx] = t2[(long)bz * 5120 + idx];
  int il = tid >> 2, cg = tid & 3;
  float a0 = 0, a1 = 0, a2 = 0;
  const float* Ab = A + (long)bz * 512 * 512;
  for (int kk0 = 0; kk0 < 512; kk0 += 32) {
    __syncthreads();
    for (int idx = tid; idx < 2048; idx += 256) {
      int r = idx >> 5, k = idx & 31;
      As[r * 33 + k] = Ab[(long)(i0 + r) * 512 + kk0 + k];
    }
    __syncthreads();
#pragma unroll 4
    for (int kk = 0; kk < 32; ++kk) {
      float av = As[il * 33 + kk];
      const float* tp = &t2s[(kk0 + kk) * 10];
      a0 = fmaf(av, tp[cg], a0);
      a1 = fmaf(av, tp[cg + 4], a1);
      if (cg < 2) a2 = fmaf(av, tp[cg + 8], a2);
    }
  }
  long ob = (long)(bz * 512 + i0 + il) * 10;
  osp[ob + cg] = reluf_(a0 + gc2_b[cg]);
  osp[ob + cg + 4] = reluf_(a1 + gc2_b[cg + 4]);
  if (cg < 2) osp[ob + cg + 8] = reluf_(a2 + gc2_b[cg + 8]);
}

// ---------------- readout + BCE loss ----------------
__global__ __launch_bounds__(256) void readout_kernel(
    const float* __restrict__ osp, const float* __restrict__ last_hid,
    const float* __restrict__ out_W, const float* __restrict__ out_b,
    const float* __restrict__ Y, float* __restrict__ d_out) {
  int tid = threadIdx.x;
  int gid = blockIdx.x * 256 + tid;  // 0..4095
  __shared__ float wS[138];
  for (int idx = tid; idx < 138; idx += 256) wS[idx] = out_W[idx];
  __syncthreads();
  float y = out_b[0];
  const float* sp = &osp[(long)gid * 10];
#pragma unroll
  for (int k = 0; k < 10; ++k) y = fmaf(sp[k], wS[k], y);
  const float* hp = &last_hid[(long)gid * 128];
  for (int h = 0; h < 128; h += 4) {
    float4 hv = *(const float4*)&hp[h];
    y = fmaf(hv.x, wS[10 + h + 0], y);
    y = fmaf(hv.y, wS[10 + h + 1], y);
    y = fmaf(hv.z, wS[10 + h + 2], y);
    y = fmaf(hv.w, wS[10 + h + 3], y);
  }
  d_out[1 + gid] = sigmoidf_(y);
  float l = fmaxf(y, 0.f) + log1pf(__expf(-fabsf(y))) - Y[gid] * y;
  for (int off = 32; off > 0; off >>= 1) l += __shfl_down(l, off);
  __shared__ float red[4];
  if ((tid & 63) == 0) red[tid >> 6] = l;
  __syncthreads();
  if (tid == 0)
    atomicAdd(d_out, (red[0] + red[1] + red[2] + red[3]) * (1.0f / 4096.f));
}

// ---------------- launcher ----------------
extern "C" void kernel_launch(void* const* d_in, const int* in_sizes, int n_in,
                              void* d_out, int out_size, void* d_ws, size_t ws_size,
                              hipStream_t stream) {
  const float* X       = (const float*)d_in[0];
  const float* Y       = (const float*)d_in[1];
  const float* adj     = (const float*)d_in[2];
  const float* V       = (const float*)d_in[3];
  const float* bv      = (const float*)d_in[4];
  const float* W1      = (const float*)d_in[5];
  const float* b1      = (const float*)d_in[6];
  const float* W2      = (const float*)d_in[7];
  const float* Wb      = (const float*)d_in[8];
  const float* wb      = (const float*)d_in[9];
  const float* conv_w  = (const float*)d_in[10];
  const float* conv_b  = (const float*)d_in[11];
  const float* convl_w = (const float*)d_in[12];
  const float* convl_b = (const float*)d_in[13];
  const float* gWih    = (const float*)d_in[14];
  const float* gWhh    = (const float*)d_in[15];
  const float* gbih    = (const float*)d_in[16];
  const float* gbhh    = (const float*)d_in[17];
  const float* gc1_W   = (const float*)d_in[18];
  const float* gc1_b   = (const float*)d_in[19];
  const float* gc2_W   = (const float*)d_in[20];
  const float* gc2_b   = (const float*)d_in[21];
  const float* out_W   = (const float*)d_in[22];
  const float* out_b   = (const float*)d_in[23];
  float* out = (float*)d_out;

  float* ws = (float*)d_ws;
  float* WhhT  = ws; ws += 49152;
  float* lhid  = ws; ws += 524288;
  float* p1    = ws; ws += 262144;
  float* p2    = ws; ws += 262144;
  float* amx   = ws; ws += 2097152;
  float* scl   = ws; ws += 4096;
  float* r_l   = ws; ws += 122880;
  float* Abuf  = ws; ws += 2097152;
  float* t1    = ws; ws += 524288;
  float* h1    = ws; ws += 524288;
  float* t2    = ws; ws += 40960;
  float* osp   = ws; ws += 40960;
  if (ws_size < (size_t)(ws - (float*)d_ws) * sizeof(float)) return;

  whht_kernel<<<192, 256, 0, stream>>>(gWhh, WhhT);
  gru_kernel<<<512, 384, 0, stream>>>(X, WhhT, gWih, gbih, gbhh, lhid);
  attn_p_kernel<<<1024, 128, 0, stream>>>(lhid, W1, W2, b1, p1, p2);
  amx_kernel<<<dim3(32, 32, 8), 256, 0, stream>>>(p1, p2, V, bv, amx);
  colnorm_kernel<<<dim3(16, 8), 256, 0, stream>>>(amx, scl);
  conv_kernel<<<512, 128, 0, stream>>>(X, conv_w, conv_b, convl_w, convl_b, r_l);
  t1_kernel<<<1024, 128, 0, stream>>>(r_l, gc1_W, t1);
  gemm_cA<<<dim3(8, 8, 8), 256, 0, stream>>>(amx, Wb, adj, wb, scl, Abuf);
  gemm_h1<<<dim3(2, 8, 8), 256, 0, stream>>>(Abuf, t1, gc1_b, h1);
  t2_kernel<<<256, 256, 0, stream>>>(h1, gc2_W, t2);
  spat_kernel<<<dim3(8, 8), 256, 0, stream>>>(Abuf, t2, gc2_b, osp);
  hipMemsetAsync(d_out, 0, sizeof(float), stream);
  readout_kernel<<<16, 256, 0, stream>>>(osp, lhid, out_W, out_b, Y, out);
}

// Round 3
// 351.919 us; speedup vs baseline: 1.6778x; 1.6778x over previous
//
#include <hip/hip_runtime.h>
#include <math.h>

// ---------------- sizes ----------------
#define Bn 8
#define Wn 20
#define Mn 512
#define Fn 16
#define Hn 128
#define HALFn 64
#define Kn 10

typedef __attribute__((ext_vector_type(8))) short short8;
typedef __attribute__((ext_vector_type(4))) float f32x4;

__device__ __forceinline__ float sigmoidf_(float x) {
  return 1.0f / (1.0f + __expf(-x));
}
__device__ __forceinline__ float tanhf_(float x) {
  float xx = fminf(fmaxf(x, -15.f), 15.f);
  float e = __expf(2.f * xx);
  return (e - 1.f) / (e + 1.f);
}
__device__ __forceinline__ float reluf_(float x) { return fmaxf(x, 0.f); }

// RNE fp32 -> bf16 bits
__device__ __forceinline__ unsigned short bf16_rne(float v) {
  unsigned u = __float_as_uint(v);
  u += 0x7FFFu + ((u >> 16) & 1u);
  return (unsigned short)(u >> 16);
}
__device__ __forceinline__ float bf16_to_f(unsigned short b) {
  return __uint_as_float(((unsigned)b) << 16);
}

// ---------------- prep: pack Whh||Wih into MFMA B-fragment order, hi/lo bf16 ----
// Bpack[nt][ks][part][lane][8]: nt 0..23 (r:0-7,z:8-15,n:16-23), ks 0..4 (K=160 padded),
// part 0=hi,1=lo. k = ks*32 + (lane>>4)*8 + j ; g = (nt&7)*16 + (nt>>3)*128 + (lane&15).
// k<128 -> Whh[g][k]; 128<=k<144 -> Wih[g][k-128]; else 0.
__global__ __launch_bounds__(256) void pack_kernel(
    const float* __restrict__ Whh, const float* __restrict__ Wih,
    unsigned short* __restrict__ Bpack) {
  int idx = blockIdx.x * 256 + threadIdx.x;   // 24*5*512 = 61440
  if (idx >= 24 * 5 * 512) return;
  int j = idx & 7;
  int lane = (idx >> 3) & 63;
  int ks = (idx >> 9) % 5;
  int nt = idx / (5 * 512);
  int k = ks * 32 + (lane >> 4) * 8 + j;
  int g = (nt & 7) * 16 + (nt >> 3) * 128 + (lane & 15);
  float val = 0.f;
  if (k < 128) val = Whh[g * 128 + k];
  else if (k < 144) val = Wih[g * 16 + (k - 128)];
  unsigned short hb = bf16_rne(val);
  float lo = val - bf16_to_f(hb);
  unsigned short lb = bf16_rne(lo);
  Bpack[(((long)nt * 5 + ks) * 2 + 0) * 512 + lane * 8 + j] = hb;
  Bpack[(((long)nt * 5 + ks) * 2 + 1) * 512 + lane * 8 + j] = lb;
}

// ---------------- GRU via split-bf16 MFMA ----------------
// 256 blocks x 512 threads. Block: 16 seqs. Wave w (0..7): gate-triple for hidden
// cols j0=w*16. B frags persistent in VGPRs (loaded once). h in LDS as hi/lo bf16
// (A-operand layout rows), x folded at k=128..143. 60 MFMA/wave/step, 2 barriers.
#define LDK 168   // padded LDS row stride (bf16 elems); 16B-aligned, 2-way banks
__global__ __launch_bounds__(512, 2) void gru_kernel(
    const float* __restrict__ X, const unsigned short* __restrict__ Bpack,
    const float* __restrict__ bih, const float* __restrict__ bhh,
    float* __restrict__ last_hid) {
  const int tid = threadIdx.x;
  const int wave = tid >> 6;
  const int lane = tid & 63;
  const int quad = lane >> 4;
  const int jl = lane & 15;
  const int j0 = wave * 16;
  const int blk = blockIdx.x;
  const int b = blk >> 5;              // 32 blocks per batch element
  const int m0 = (blk & 31) * 16;

  __shared__ unsigned short h_hi[16 * LDK];
  __shared__ unsigned short h_lo[16 * LDK];

  // ---- persistent B fragments ----
  short8 frR[5][2], frZ[5][2], frN[4][2], frXN[2];
#pragma unroll
  for (int ks = 0; ks < 5; ++ks) {
#pragma unroll
    for (int p = 0; p < 2; ++p) {
      frR[ks][p] = *(const short8*)&Bpack[(((long)(wave) * 5 + ks) * 2 + p) * 512 + lane * 8];
      frZ[ks][p] = *(const short8*)&Bpack[(((long)(8 + wave) * 5 + ks) * 2 + p) * 512 + lane * 8];
    }
  }
#pragma unroll
  for (int ks = 0; ks < 4; ++ks) {
#pragma unroll
    for (int p = 0; p < 2; ++p)
      frN[ks][p] = *(const short8*)&Bpack[(((long)(16 + wave) * 5 + ks) * 2 + p) * 512 + lane * 8];
  }
#pragma unroll
  for (int p = 0; p < 2; ++p)
    frXN[p] = *(const short8*)&Bpack[(((long)(16 + wave) * 5 + 4) * 2 + p) * 512 + lane * 8];

  const float cr  = bih[j0 + jl] + bhh[j0 + jl];
  const float cz  = bih[128 + j0 + jl] + bhh[128 + j0 + jl];
  const float cnx = bih[256 + j0 + jl];
  const float cnh = bhh[256 + j0 + jl];

  // zero LDS (h rows 0..127 = h0=0; pad rows stay 0 so garbage never feeds MFMA)
  for (int i = tid; i < 16 * LDK; i += 512) { h_hi[i] = 0; h_lo[i] = 0; }

  const float* Xb = X + (long)b * (Wn * Mn * Fn) + (long)m0 * Fn;
  float x0 = 0.f;
  if (tid < 256) x0 = Xb[tid];          // s=tid>>4, f=tid&15 (coalesced)
  __syncthreads();
  if (tid < 256) {
    int s = tid >> 4, f = tid & 15;
    unsigned short hb = bf16_rne(x0);
    unsigned short lb = bf16_rne(x0 - bf16_to_f(hb));
    h_hi[s * LDK + 128 + f] = hb;
    h_lo[s * LDK + 128 + f] = lb;
  }
  __syncthreads();

  float hp[4] = {0.f, 0.f, 0.f, 0.f};

  for (int t = 0; t < Wn; ++t) {
    // prefetch next x tile (global, hidden under MFMAs)
    float xpre = 0.f;
    {
      int tt = (t < Wn - 1) ? (t + 1) : (Wn - 1);
      if (tid < 256) xpre = Xb[(long)tt * (Mn * Fn) + tid];
    }

    f32x4 aR = {0.f, 0.f, 0.f, 0.f}, aZ = {0.f, 0.f, 0.f, 0.f};
    f32x4 aHN = {0.f, 0.f, 0.f, 0.f}, aXN = {0.f, 0.f, 0.f, 0.f};
#pragma unroll
    for (int ks = 0; ks < 5; ++ks) {
      short8 ah = *(const short8*)&h_hi[jl * LDK + ks * 32 + quad * 8];
      short8 al = *(const short8*)&h_lo[jl * LDK + ks * 32 + quad * 8];
      aR = __builtin_amdgcn_mfma_f32_16x16x32_bf16(ah, frR[ks][0], aR, 0, 0, 0);
      aR = __builtin_amdgcn_mfma_f32_16x16x32_bf16(ah, frR[ks][1], aR, 0, 0, 0);
      aR = __builtin_amdgcn_mfma_f32_16x16x32_bf16(al, frR[ks][0], aR, 0, 0, 0);
      aR = __builtin_amdgcn_mfma_f32_16x16x32_bf16(al, frR[ks][1], aR, 0, 0, 0);
      aZ = __builtin_amdgcn_mfma_f32_16x16x32_bf16(ah, frZ[ks][0], aZ, 0, 0, 0);
      aZ = __builtin_amdgcn_mfma_f32_16x16x32_bf16(ah, frZ[ks][1], aZ, 0, 0, 0);
      aZ = __builtin_amdgcn_mfma_f32_16x16x32_bf16(al, frZ[ks][0], aZ, 0, 0, 0);
      aZ = __builtin_amdgcn_mfma_f32_16x16x32_bf16(al, frZ[ks][1], aZ, 0, 0, 0);
      if (ks < 4) {
        aHN = __builtin_amdgcn_mfma_f32_16x16x32_bf16(ah, frN[ks][0], aHN, 0, 0, 0);
        aHN = __builtin_amdgcn_mfma_f32_16x16x32_bf16(ah, frN[ks][1], aHN, 0, 0, 0);
        aHN = __builtin_amdgcn_mfma_f32_16x16x32_bf16(al, frN[ks][0], aHN, 0, 0, 0);
        aHN = __builtin_amdgcn_mfma_f32_16x16x32_bf16(al, frN[ks][1], aHN, 0, 0, 0);
      } else {
        aXN = __builtin_amdgcn_mfma_f32_16x16x32_bf16(ah, frXN[0], aXN, 0, 0, 0);
        aXN = __builtin_amdgcn_mfma_f32_16x16x32_bf16(ah, frXN[1], aXN, 0, 0, 0);
        aXN = __builtin_amdgcn_mfma_f32_16x16x32_bf16(al, frXN[0], aXN, 0, 0, 0);
        aXN = __builtin_amdgcn_mfma_f32_16x16x32_bf16(al, frXN[1], aXN, 0, 0, 0);
      }
    }
    __syncthreads();   // all waves' MFMA reads of h/x done

    // gate math: lane owns seqs quad*4+reg, hidden col j0+jl
#pragma unroll
    for (int reg = 0; reg < 4; ++reg) {
      float r = sigmoidf_(aR[reg] + cr);
      float z = sigmoidf_(aZ[reg] + cz);
      float n = tanhf_(aXN[reg] + cnx + r * (aHN[reg] + cnh));
      float h = (1.f - z) * n + z * hp[reg];
      hp[reg] = h;
      int s = quad * 4 + reg;
      unsigned short hb = bf16_rne(h);
      unsigned short lb = bf16_rne(h - bf16_to_f(hb));
      h_hi[s * LDK + j0 + jl] = hb;
      h_lo[s * LDK + j0 + jl] = lb;
    }
    if (tid < 256 && t < Wn - 1) {
      int s = tid >> 4, f = tid & 15;
      unsigned short hb = bf16_rne(xpre);
      unsigned short lb = bf16_rne(xpre - bf16_to_f(hb));
      h_hi[s * LDK + 128 + f] = hb;
      h_lo[s * LDK + 128 + f] = lb;
    }
    __syncthreads();   // h(t+1)/x(t+1) visible
  }

#pragma unroll
  for (int reg = 0; reg < 4; ++reg) {
    int s = quad * 4 + reg;
    last_hid[(long)(blk * 16 + s) * Hn + j0 + jl] = hp[reg];
  }
}

// ---------------- p1/p2: per-row projections (4 rows/block) ----------------
__global__ __launch_bounds__(128) void attn_p_kernel(
    const float* __restrict__ last_hid, const float* __restrict__ W1,
    const float* __restrict__ W2, const float* __restrict__ b1,
    float* __restrict__ p1, float* __restrict__ p2) {
  int r0 = blockIdx.x * 4;
  int t = threadIdx.x;
  __shared__ float hs[4][128];
  for (int idx = t; idx < 512; idx += 128)
    hs[idx >> 7][idx & 127] = last_hid[(long)r0 * 128 + idx];
  __syncthreads();
  int k = t & 63;
  const float* Wp = (t < 64) ? W1 : W2;
  float a0, a1, a2, a3;
  a0 = a1 = a2 = a3 = (t < 64) ? b1[k] : 0.f;
  for (int h = 0; h < 128; h += 4) {
    float4 w = *(const float4*)&Wp[k * 128 + h];
    float4 q0 = *(const float4*)&hs[0][h];
    float4 q1 = *(const float4*)&hs[1][h];
    float4 q2 = *(const float4*)&hs[2][h];
    float4 q3 = *(const float4*)&hs[3][h];
    a0 += q0.x * w.x + q0.y * w.y + q0.z * w.z + q0.w * w.w;
    a1 += q1.x * w.x + q1.y * w.y + q1.z * w.z + q1.w * w.w;
    a2 += q2.x * w.x + q2.y * w.y + q2.z * w.z + q2.w * w.w;
    a3 += q3.x * w.x + q3.y * w.y + q3.z * w.z + q3.w * w.w;
  }
  float* outp = (t < 64) ? p1 : p2;
  outp[(r0 + 0) * 64 + k] = a0;
  outp[(r0 + 1) * 64 + k] = a1;
  outp[(r0 + 2) * 64 + k] = a2;
  outp[(r0 + 3) * 64 + k] = a3;
}

// ---------------- a_mx (raw): 16x16 tile per block ----------------
__global__ __launch_bounds__(256) void amx_kernel(
    const float* __restrict__ p1, const float* __restrict__ p2,
    const float* __restrict__ V, const float* __restrict__ bv,
    float* __restrict__ amx) {
  int tid = threadIdx.x;
  int j0 = blockIdx.x * 16, i0 = blockIdx.y * 16, bz = blockIdx.z;
  __shared__ float p1s[16][68];
  __shared__ float p2s[16][68];
  __shared__ float Vs[64];
  if (tid < 64) Vs[tid] = V[tid];
#pragma unroll
  for (int l = 0; l < 4; ++l) {
    int idx = l * 256 + tid;
    int rr = idx >> 6, k = idx & 63;
    p1s[rr][k] = p1[(long)(bz * 512 + j0 + rr) * 64 + k];
    p2s[rr][k] = p2[(long)(bz * 512 + i0 + rr) * 64 + k];
  }
  __syncthreads();
  int ii = tid >> 4, jj = tid & 15;
  float acc = 0.f;
#pragma unroll 4
  for (int k = 0; k < 64; ++k) {
    float pre = p1s[jj][k] + p2s[ii][k];
    float e = (pre > 0.f) ? pre : (__expf(pre) - 1.f);
    acc = fmaf(e, Vs[k], acc);
  }
  amx[((long)bz * 512 + i0 + ii) * 512 + j0 + jj] = acc + bv[0];
}

// ---------------- column L2 norm over i (dim=1) -> reciprocal scale ----------------
__global__ __launch_bounds__(256) void colnorm_kernel(const float* __restrict__ amx,
                                                      float* __restrict__ scale) {
  int b = blockIdx.y;
  int j0 = blockIdx.x * 32;
  int jl = threadIdx.x & 31, ip = threadIdx.x >> 5;
  const float* base = amx + (long)b * 512 * 512;
  float ss = 0.f;
  for (int i = ip; i < 512; i += 8) {
    float v = base[(long)i * 512 + j0 + jl];
    ss = fmaf(v, v, ss);
  }
  __shared__ float red[8][33];
  red[ip][jl] = ss;
  __syncthreads();
  if (threadIdx.x < 32) {
    float s = 0.f;
#pragma unroll
    for (int p = 0; p < 8; ++p) s += red[p][threadIdx.x];
    scale[b * 512 + j0 + threadIdx.x] = 1.f / fmaxf(sqrtf(s), 1e-12f);
  }
}

// ---------------- per-node convs -> r_l (b,m,30) ----------------
__global__ __launch_bounds__(128) void conv_kernel(
    const float* __restrict__ X, const float* __restrict__ conv_w,
    const float* __restrict__ conv_b, const float* __restrict__ convl_w,
    const float* __restrict__ convl_b, float* __restrict__ r_l) {
  int tid = threadIdx.x;
  int n0 = blockIdx.x * 8;
  int b = n0 >> 9, m0 = n0 & 511;
  __shared__ float xs[8][16][20];
  __shared__ float cw[3200];
  __shared__ float clw[1600];
  for (int idx = tid; idx < 3200; idx += 128) cw[idx] = conv_w[idx];
  for (int idx = tid; idx < 1600; idx += 128) clw[idx] = convl_w[idx];
  for (int w = 0; w < 20; ++w)
    xs[tid >> 4][tid & 15][w] = X[((long)(b * 20 + w) * 512 + m0) * 16 + tid];
  __syncthreads();
  if (tid < 80) {
    int s = tid / 10, k = tid % 10;
    float a0 = conv_b[k];
    float l0 = convl_b[k], l1 = convl_b[k];
    for (int f = 0; f < 16; ++f) {
#pragma unroll
      for (int w = 0; w < 20; ++w) a0 = fmaf(xs[s][f][w], cw[k * 320 + f * 20 + w], a0);
#pragma unroll
      for (int q = 0; q < 10; ++q) {
        float wv = clw[k * 160 + f * 10 + q];
        l0 = fmaf(xs[s][f][2 * q], wv, l0);
        l1 = fmaf(xs[s][f][2 * q + 1], wv, l1);
      }
    }
    long base = (long)(n0 + s) * 30 + k * 3;
    r_l[base + 0] = reluf_(a0);
    r_l[base + 1] = reluf_(l0);
    r_l[base + 2] = reluf_(l1);
  }
}

// ---------------- t1 = r_l @ gc1_W  (4 rows/block) ----------------
__global__ __launch_bounds__(128) void t1_kernel(const float* __restrict__ r_l,
                                                 const float* __restrict__ gc1_W,
                                                 float* __restrict__ t1) {
  int r0 = blockIdx.x * 4;
  int h = threadIdx.x;
  __shared__ float rs[4][30];
  if (h < 120) rs[h / 30][h % 30] = r_l[(long)r0 * 30 + h];
  __syncthreads();
  float a0 = 0, a1 = 0, a2 = 0, a3 = 0;
#pragma unroll
  for (int q = 0; q < 30; ++q) {
    float w = gc1_W[q * 128 + h];
    a0 = fmaf(rs[0][q], w, a0);
    a1 = fmaf(rs[1][q], w, a1);
    a2 = fmaf(rs[2][q], w, a2);
    a3 = fmaf(rs[3][q], w, a3);
  }
  t1[(long)(r0 + 0) * 128 + h] = a0;
  t1[(long)(r0 + 1) * 128 + h] = a1;
  t1[(long)(r0 + 2) * 128 + h] = a2;
  t1[(long)(r0 + 3) * 128 + h] = a3;
}

// ---- gemm: c = sigmoid((amx*scl)@Wb + wb); A = adj*c + (amx*scl)*(1-c) ----
__global__ __launch_bounds__(256) void gemm_cA(
    const float* __restrict__ amx, const float* __restrict__ Wb,
    const float* __restrict__ adj, const float* __restrict__ wb,
    const float* __restrict__ scl, float* __restrict__ A) {
  const int bz = blockIdx.z;
  const int i0 = blockIdx.y * 64;
  const int j0 = blockIdx.x * 64;
  const int tid = threadIdx.x;
  const int ti = tid >> 4, tj = tid & 15;
  __shared__ float As[16][64];
  __shared__ float Bs[16][64];
  float acc[4][4] = {};
  const float* Abase = amx + (long)bz * 512 * 512;
  const float* sbase = scl + bz * 512;
  for (int kk0 = 0; kk0 < 512; kk0 += 16) {
    __syncthreads();
    {
      int il = tid >> 2, kq = (tid & 3) * 4;
      float4 v = *(const float4*)&Abase[(long)(i0 + il) * 512 + kk0 + kq];
      float4 sc = *(const float4*)&sbase[kk0 + kq];
      As[kq + 0][il] = v.x * sc.x; As[kq + 1][il] = v.y * sc.y;
      As[kq + 2][il] = v.z * sc.z; As[kq + 3][il] = v.w * sc.w;
      int kk = tid >> 4, jl = (tid & 15) * 4;
      *(float4*)&Bs[kk][jl] = *(const float4*)&Wb[(long)(kk0 + kk) * 512 + j0 + jl];
    }
    __syncthreads();
#pragma unroll
    for (int k = 0; k < 16; ++k) {
      float4 a4 = *(const float4*)&As[k][ti * 4];
      float4 b4 = *(const float4*)&Bs[k][tj * 4];
      float av[4] = {a4.x, a4.y, a4.z, a4.w};
      float bw[4] = {b4.x, b4.y, b4.z, b4.w};
#pragma unroll
      for (int a = 0; a < 4; ++a)
#pragma unroll
        for (int c = 0; c < 4; ++c) acc[a][c] = fmaf(av[a], bw[c], acc[a][c]);
    }
  }
  const float wbv = wb[0];
  float4 sj = *(const float4*)&sbase[j0 + tj * 4];
#pragma unroll
  for (int a = 0; a < 4; ++a) {
    int i = i0 + ti * 4 + a;
    long idx4 = (long)bz * 512 * 512 + (long)i * 512 + j0 + tj * 4;
    float4 am = *(const float4*)&amx[idx4];
    am.x *= sj.x; am.y *= sj.y; am.z *= sj.z; am.w *= sj.w;
    float4 ad = *(const float4*)&adj[(long)i * 512 + j0 + tj * 4];
    float4 o;
    float c0 = sigmoidf_(acc[a][0] + wbv);
    float c1 = sigmoidf_(acc[a][1] + wbv);
    float c2 = sigmoidf_(acc[a][2] + wbv);
    float c3 = sigmoidf_(acc[a][3] + wbv);
    o.x = ad.x * c0 + am.x * (1.f - c0);
    o.y = ad.y * c1 + am.y * (1.f - c1);
    o.z = ad.z * c2 + am.z * (1.f - c2);
    o.w = ad.w * c3 + am.w * (1.f - c3);
    *(float4*)&A[idx4] = o;
  }
}

// ---------------- gemm: h1 = relu(A @ t1 + gc1_b) ----------------
__global__ __launch_bounds__(256) void gemm_h1(
    const float* __restrict__ A, const float* __restrict__ t1,
    const float* __restrict__ gc1_b, float* __restrict__ h1) {
  const int bz = blockIdx.z;
  const int i0 = blockIdx.y * 64;
  const int j0 = blockIdx.x * 64;
  const int tid = threadIdx.x;
  const int ti = tid >> 4, tj = tid & 15;
  __shared__ float As[16][64];
  __shared__ float Bs[16][64];
  float acc[4][4] = {};
  const float* Abase = A + (long)bz * 512 * 512;
  const float* Bbase = t1 + (long)bz * 512 * 128;
  for (int kk0 = 0; kk0 < 512; kk0 += 16) {
    __syncthreads();
    {
      int il = tid >> 2, kq = (tid & 3) * 4;
      float4 v = *(const float4*)&Abase[(long)(i0 + il) * 512 + kk0 + kq];
      As[kq + 0][il] = v.x; As[kq + 1][il] = v.y;
      As[kq + 2][il] = v.z; As[kq + 3][il] = v.w;
      int kk = tid >> 4, jl = (tid & 15) * 4;
      *(float4*)&Bs[kk][jl] = *(const float4*)&Bbase[(long)(kk0 + kk) * 128 + j0 + jl];
    }
    __syncthreads();
#pragma unroll
    for (int k = 0; k < 16; ++k) {
      float4 a4 = *(const float4*)&As[k][ti * 4];
      float4 b4 = *(const float4*)&Bs[k][tj * 4];
      float av[4] = {a4.x, a4.y, a4.z, a4.w};
      float bw[4] = {b4.x, b4.y, b4.z, b4.w};
#pragma unroll
      for (int a = 0; a < 4; ++a)
#pragma unroll
        for (int c = 0; c < 4; ++c) acc[a][c] = fmaf(av[a], bw[c], acc[a][c]);
    }
  }
#pragma unroll
  for (int a = 0; a < 4; ++a) {
    int i = i0 + ti * 4 + a;
    int jj = j0 + tj * 4;
    float4 o;
    o.x = reluf_(acc[a][0] + gc1_b[jj + 0]);
    o.y = reluf_(acc[a][1] + gc1_b[jj + 1]);
    o.z = reluf_(acc[a][2] + gc1_b[jj + 2]);
    o.w = reluf_(acc[a][3] + gc1_b[jj + 3]);
    *(float4*)&h1[((long)bz * 512 + i) * 128 + jj] = o;
  }
}

// ---------------- t2 = h1 @ gc2_W (16 rows/block) ----------------
__global__ __launch_bounds__(256) void t2_kernel(const float* __restrict__ h1,
                                                 const float* __restrict__ gc2_W,
                                                 float* __restrict__ t2) {
  int tid = threadIdx.x;
  int r0 = blockIdx.x * 16;
  __shared__ float hs[16 * 129];
  __shared__ float wsh[1280];
  for (int idx = tid; idx < 2048; idx += 256) {
    int r = idx >> 7, k = idx & 127;
    hs[r * 129 + k] = h1[(long)(r0 + r) * 128 + k];
  }
  for (int idx = tid; idx < 1280; idx += 256) wsh[idx] = gc2_W[idx];
  __syncthreads();
  if (tid < 160) {
    int r = tid / 10, c = tid % 10;
    float a = 0.f;
#pragma unroll 4
    for (int k = 0; k < 128; ++k) a = fmaf(hs[r * 129 + k], wsh[k * 10 + c], a);
    t2[(long)(r0 + r) * 10 + c] = a;
  }
}

// ---------------- out_spatial = relu(A @ t2 + gc2_b) ----------------
__global__ __launch_bounds__(256) void spat_kernel(
    const float* __restrict__ A, const float* __restrict__ t2,
    const float* __restrict__ gc2_b, float* __restrict__ osp) {
  int tid = threadIdx.x;
  int bz = blockIdx.y;
  int i0 = blockIdx.x * 64;
  __shared__ float t2s[5120];
  __shared__ float As[64 * 33];
  for (int idx = tid; idx < 5120; idx += 256) t2s[idx] = t2[(long)bz * 5120 + idx];
  int il = tid >> 2, cg = tid & 3;
  float a0 = 0, a1 = 0, a2 = 0;
  const float* Ab = A + (long)bz * 512 * 512;
  for (int kk0 = 0; kk0 < 512; kk0 += 32) {
    __syncthreads();
    for (int idx = tid; idx < 2048; idx += 256) {
      int r = idx >> 5, k = idx & 31;
      As[r * 33 + k] = Ab[(long)(i0 + r) * 512 + kk0 + k];
    }
    __syncthreads();
#pragma unroll 4
    for (int kk = 0; kk < 32; ++kk) {
      float av = As[il * 33 + kk];
      const float* tp = &t2s[(kk0 + kk) * 10];
      a0 = fmaf(av, tp[cg], a0);
      a1 = fmaf(av, tp[cg + 4], a1);
      if (cg < 2) a2 = fmaf(av, tp[cg + 8], a2);
    }
  }
  long ob = (long)(bz * 512 + i0 + il) * 10;
  osp[ob + cg] = reluf_(a0 + gc2_b[cg]);
  osp[ob + cg + 4] = reluf_(a1 + gc2_b[cg + 4]);
  if (cg < 2) osp[ob + cg + 8] = reluf_(a2 + gc2_b[cg + 8]);
}

// ---------------- readout + BCE loss ----------------
__global__ __launch_bounds__(256) void readout_kernel(
    const float* __restrict__ osp, const float* __restrict__ last_hid,
    const float* __restrict__ out_W, const float* __restrict__ out_b,
    const float* __restrict__ Y, float* __restrict__ d_out) {
  int tid = threadIdx.x;
  int gid = blockIdx.x * 256 + tid;
  __shared__ float wS[138];
  for (int idx = tid; idx < 138; idx += 256) wS[idx] = out_W[idx];
  __syncthreads();
  float y = out_b[0];
  const float* sp = &osp[(long)gid * 10];
#pragma unroll
  for (int k = 0; k < 10; ++k) y = fmaf(sp[k], wS[k], y);
  const float* hp = &last_hid[(long)gid * 128];
  for (int h = 0; h < 128; h += 4) {
    float4 hv = *(const float4*)&hp[h];
    y = fmaf(hv.x, wS[10 + h + 0], y);
    y = fmaf(hv.y, wS[10 + h + 1], y);
    y = fmaf(hv.z, wS[10 + h + 2], y);
    y = fmaf(hv.w, wS[10 + h + 3], y);
  }
  d_out[1 + gid] = sigmoidf_(y);
  float l = fmaxf(y, 0.f) + log1pf(__expf(-fabsf(y))) - Y[gid] * y;
  for (int off = 32; off > 0; off >>= 1) l += __shfl_down(l, off);
  __shared__ float red[4];
  if ((tid & 63) == 0) red[tid >> 6] = l;
  __syncthreads();
  if (tid == 0)
    atomicAdd(d_out, (red[0] + red[1] + red[2] + red[3]) * (1.0f / 4096.f));
}

// ---------------- launcher ----------------
extern "C" void kernel_launch(void* const* d_in, const int* in_sizes, int n_in,
                              void* d_out, int out_size, void* d_ws, size_t ws_size,
                              hipStream_t stream) {
  const float* X       = (const float*)d_in[0];
  const float* Y       = (const float*)d_in[1];
  const float* adj     = (const float*)d_in[2];
  const float* V       = (const float*)d_in[3];
  const float* bv      = (const float*)d_in[4];
  const float* W1      = (const float*)d_in[5];
  const float* b1      = (const float*)d_in[6];
  const float* W2      = (const float*)d_in[7];
  const float* Wb      = (const float*)d_in[8];
  const float* wb      = (const float*)d_in[9];
  const float* conv_w  = (const float*)d_in[10];
  const float* conv_b  = (const float*)d_in[11];
  const float* convl_w = (const float*)d_in[12];
  const float* convl_b = (const float*)d_in[13];
  const float* gWih    = (const float*)d_in[14];
  const float* gWhh    = (const float*)d_in[15];
  const float* gbih    = (const float*)d_in[16];
  const float* gbhh    = (const float*)d_in[17];
  const float* gc1_W   = (const float*)d_in[18];
  const float* gc1_b   = (const float*)d_in[19];
  const float* gc2_W   = (const float*)d_in[20];
  const float* gc2_b   = (const float*)d_in[21];
  const float* out_W   = (const float*)d_in[22];
  const float* out_b   = (const float*)d_in[23];
  float* out = (float*)d_out;

  float* ws = (float*)d_ws;
  float* lhid  = ws; ws += 524288;
  float* p1    = ws; ws += 262144;
  float* p2    = ws; ws += 262144;
  float* amx   = ws; ws += 2097152;
  float* scl   = ws; ws += 4096;
  float* r_l   = ws; ws += 122880;
  float* Abuf  = ws; ws += 2097152;
  float* t1    = ws; ws += 524288;
  float* h1    = ws; ws += 524288;
  float* t2    = ws; ws += 40960;
  float* osp   = ws; ws += 40960;
  if (ws_size < (size_t)(ws - (float*)d_ws) * sizeof(float)) return;
  // Bpack (491,520 B) aliases h1's region: written by pack_kernel (launch 1),
  // read by gru_kernel (launch 2); h1 isn't written until gemm_h1 (launch 9).
  unsigned short* Bpack = (unsigned short*)h1;

  pack_kernel<<<240, 256, 0, stream>>>(gWhh, gWih, Bpack);
  gru_kernel<<<256, 512, 0, stream>>>(X, Bpack, gbih, gbhh, lhid);
  attn_p_kernel<<<1024, 128, 0, stream>>>(lhid, W1, W2, b1, p1, p2);
  amx_kernel<<<dim3(32, 32, 8), 256, 0, stream>>>(p1, p2, V, bv, amx);
  colnorm_kernel<<<dim3(16, 8), 256, 0, stream>>>(amx, scl);
  conv_kernel<<<512, 128, 0, stream>>>(X, conv_w, conv_b, convl_w, convl_b, r_l);
  t1_kernel<<<1024, 128, 0, stream>>>(r_l, gc1_W, t1);
  gemm_cA<<<dim3(8, 8, 8), 256, 0, stream>>>(amx, Wb, adj, wb, scl, Abuf);
  gemm_h1<<<dim3(2, 8, 8), 256, 0, stream>>>(Abuf, t1, gc1_b, h1);
  t2_kernel<<<256, 256, 0, stream>>>(h1, gc2_W, t2);
  spat_kernel<<<dim3(8, 8), 256, 0, stream>>>(Abuf, t2, gc2_b, osp);
  hipMemsetAsync(d_out, 0, sizeof(float), stream);
  readout_kernel<<<16, 256, 0, stream>>>(osp, lhid, out_W, out_b, Y, out);
}

// Round 4
// 339.966 us; speedup vs baseline: 1.7367x; 1.0352x over previous
//
#include <hip/hip_runtime.h>
#include <math.h>

// ---------------- sizes ----------------
#define Bn 8
#define Wn 20
#define Mn 512
#define Fn 16
#define Hn 128
#define HALFn 64
#define Kn 10

typedef __attribute__((ext_vector_type(8))) short short8;
typedef __attribute__((ext_vector_type(4))) float f32x4;

__device__ __forceinline__ float sigmoidf_(float x) {
  return 1.0f / (1.0f + __expf(-x));
}
__device__ __forceinline__ float tanhf_(float x) {
  float xx = fminf(fmaxf(x, -15.f), 15.f);
  float e = __expf(2.f * xx);
  return (e - 1.f) / (e + 1.f);
}
__device__ __forceinline__ float reluf_(float x) { return fmaxf(x, 0.f); }
__device__ __forceinline__ float eluf_(float x) {
  return (x > 0.f) ? x : (__expf(x) - 1.f);
}

// RNE fp32 -> bf16 bits
__device__ __forceinline__ unsigned short bf16_rne(float v) {
  unsigned u = __float_as_uint(v);
  u += 0x7FFFu + ((u >> 16) & 1u);
  return (unsigned short)(u >> 16);
}
__device__ __forceinline__ float bf16_to_f(unsigned short b) {
  return __uint_as_float(((unsigned)b) << 16);
}

// ---------------- prep: pack Whh||Wih into MFMA B-fragment order, hi/lo bf16 ----
// Also zeroes the ssq accumulator and the loss slot (fused init).
__global__ __launch_bounds__(256) void pack_kernel(
    const float* __restrict__ Whh, const float* __restrict__ Wih,
    unsigned short* __restrict__ Bpack, float* __restrict__ ssq,
    float* __restrict__ d_out) {
  int idx = blockIdx.x * 256 + threadIdx.x;   // 24*5*512 = 61440
  if (idx < 4096) ssq[idx] = 0.f;
  if (idx == 0) d_out[0] = 0.f;
  if (idx >= 24 * 5 * 512) return;
  int j = idx & 7;
  int lane = (idx >> 3) & 63;
  int ks = (idx >> 9) % 5;
  int nt = idx / (5 * 512);
  int k = ks * 32 + (lane >> 4) * 8 + j;
  int g = (nt & 7) * 16 + (nt >> 3) * 128 + (lane & 15);
  float val = 0.f;
  if (k < 128) val = Whh[g * 128 + k];
  else if (k < 144) val = Wih[g * 16 + (k - 128)];
  unsigned short hb = bf16_rne(val);
  float lo = val - bf16_to_f(hb);
  unsigned short lb = bf16_rne(lo);
  Bpack[(((long)nt * 5 + ks) * 2 + 0) * 512 + lane * 8 + j] = hb;
  Bpack[(((long)nt * 5 + ks) * 2 + 1) * 512 + lane * 8 + j] = lb;
}

// ---------------- GRU via split-bf16 MFMA + fused attn-projection epilogue ----
// 256 blocks x 512 threads. Block: 16 seqs. Wave w: gate-triple for hidden cols
// w*16. B frags persistent in VGPRs. h in LDS hi/lo bf16, x folded at k=128..143.
// 45 MFMA/wave/step (lo x lo dropped: error ~2^-18 rel, negligible).
// Epilogue: p1 = h@W1^T + b1, p2 = h@W2^T from the on-chip h tile.
#define LDK 168
__global__ __launch_bounds__(512, 2) void gru_kernel(
    const float* __restrict__ X, const unsigned short* __restrict__ Bpack,
    const float* __restrict__ bih, const float* __restrict__ bhh,
    const float* __restrict__ W1, const float* __restrict__ W2,
    const float* __restrict__ b1, float* __restrict__ last_hid,
    float* __restrict__ p1, float* __restrict__ p2) {
  const int tid = threadIdx.x;
  const int wave = tid >> 6;
  const int lane = tid & 63;
  const int quad = lane >> 4;
  const int jl = lane & 15;
  const int j0 = wave * 16;
  const int blk = blockIdx.x;
  const int b = blk >> 5;
  const int m0 = (blk & 31) * 16;

  __shared__ __align__(16) unsigned short smem_hs[2 * 16 * LDK];
  unsigned short* h_hi = smem_hs;
  unsigned short* h_lo = smem_hs + 16 * LDK;

  // ---- persistent B fragments ----
  short8 frR[5][2], frZ[5][2], frN[4][2], frXN[2];
#pragma unroll
  for (int ks = 0; ks < 5; ++ks) {
#pragma unroll
    for (int p = 0; p < 2; ++p) {
      frR[ks][p] = *(const short8*)&Bpack[(((long)(wave) * 5 + ks) * 2 + p) * 512 + lane * 8];
      frZ[ks][p] = *(const short8*)&Bpack[(((long)(8 + wave) * 5 + ks) * 2 + p) * 512 + lane * 8];
    }
  }
#pragma unroll
  for (int ks = 0; ks < 4; ++ks) {
#pragma unroll
    for (int p = 0; p < 2; ++p)
      frN[ks][p] = *(const short8*)&Bpack[(((long)(16 + wave) * 5 + ks) * 2 + p) * 512 + lane * 8];
  }
#pragma unroll
  for (int p = 0; p < 2; ++p)
    frXN[p] = *(const short8*)&Bpack[(((long)(16 + wave) * 5 + 4) * 2 + p) * 512 + lane * 8];

  const float cr  = bih[j0 + jl] + bhh[j0 + jl];
  const float cz  = bih[128 + j0 + jl] + bhh[128 + j0 + jl];
  const float cnx = bih[256 + j0 + jl];
  const float cnh = bhh[256 + j0 + jl];

  for (int i = tid; i < 16 * LDK; i += 512) { h_hi[i] = 0; h_lo[i] = 0; }

  const float* Xb = X + (long)b * (Wn * Mn * Fn) + (long)m0 * Fn;
  float x0 = 0.f;
  if (tid < 256) x0 = Xb[tid];
  __syncthreads();
  if (tid < 256) {
    int s = tid >> 4, f = tid & 15;
    unsigned short hb = bf16_rne(x0);
    unsigned short lb = bf16_rne(x0 - bf16_to_f(hb));
    h_hi[s * LDK + 128 + f] = hb;
    h_lo[s * LDK + 128 + f] = lb;
  }
  __syncthreads();

  float hp[4] = {0.f, 0.f, 0.f, 0.f};

  for (int t = 0; t < Wn; ++t) {
    float xpre = 0.f;
    {
      int tt = (t < Wn - 1) ? (t + 1) : (Wn - 1);
      if (tid < 256) xpre = Xb[(long)tt * (Mn * Fn) + tid];
    }

    f32x4 aR = {0.f, 0.f, 0.f, 0.f}, aZ = {0.f, 0.f, 0.f, 0.f};
    f32x4 aHN = {0.f, 0.f, 0.f, 0.f}, aXN = {0.f, 0.f, 0.f, 0.f};
#pragma unroll
    for (int ks = 0; ks < 5; ++ks) {
      short8 ah = *(const short8*)&h_hi[jl * LDK + ks * 32 + quad * 8];
      short8 al = *(const short8*)&h_lo[jl * LDK + ks * 32 + quad * 8];
      aR = __builtin_amdgcn_mfma_f32_16x16x32_bf16(ah, frR[ks][0], aR, 0, 0, 0);
      aR = __builtin_amdgcn_mfma_f32_16x16x32_bf16(ah, frR[ks][1], aR, 0, 0, 0);
      aR = __builtin_amdgcn_mfma_f32_16x16x32_bf16(al, frR[ks][0], aR, 0, 0, 0);
      aZ = __builtin_amdgcn_mfma_f32_16x16x32_bf16(ah, frZ[ks][0], aZ, 0, 0, 0);
      aZ = __builtin_amdgcn_mfma_f32_16x16x32_bf16(ah, frZ[ks][1], aZ, 0, 0, 0);
      aZ = __builtin_amdgcn_mfma_f32_16x16x32_bf16(al, frZ[ks][0], aZ, 0, 0, 0);
      if (ks < 4) {
        aHN = __builtin_amdgcn_mfma_f32_16x16x32_bf16(ah, frN[ks][0], aHN, 0, 0, 0);
        aHN = __builtin_amdgcn_mfma_f32_16x16x32_bf16(ah, frN[ks][1], aHN, 0, 0, 0);
        aHN = __builtin_amdgcn_mfma_f32_16x16x32_bf16(al, frN[ks][0], aHN, 0, 0, 0);
      } else {
        aXN = __builtin_amdgcn_mfma_f32_16x16x32_bf16(ah, frXN[0], aXN, 0, 0, 0);
        aXN = __builtin_amdgcn_mfma_f32_16x16x32_bf16(ah, frXN[1], aXN, 0, 0, 0);
        aXN = __builtin_amdgcn_mfma_f32_16x16x32_bf16(al, frXN[0], aXN, 0, 0, 0);
      }
    }
    __syncthreads();

#pragma unroll
    for (int reg = 0; reg < 4; ++reg) {
      float r = sigmoidf_(aR[reg] + cr);
      float z = sigmoidf_(aZ[reg] + cz);
      float n = tanhf_(aXN[reg] + cnx + r * (aHN[reg] + cnh));
      float h = (1.f - z) * n + z * hp[reg];
      hp[reg] = h;
      int s = quad * 4 + reg;
      unsigned short hb = bf16_rne(h);
      unsigned short lb = bf16_rne(h - bf16_to_f(hb));
      h_hi[s * LDK + j0 + jl] = hb;
      h_lo[s * LDK + j0 + jl] = lb;
    }
    if (tid < 256 && t < Wn - 1) {
      int s = tid >> 4, f = tid & 15;
      unsigned short hb = bf16_rne(xpre);
      unsigned short lb = bf16_rne(xpre - bf16_to_f(hb));
      h_hi[s * LDK + 128 + f] = hb;
      h_lo[s * LDK + 128 + f] = lb;
    }
    __syncthreads();
  }

  // ---- epilogue: write last_hid; stage fp32 h tile (aliases h_hi/h_lo) ----
  float* hs_f = (float*)smem_hs;          // 16 x 132 floats = 8448 B <= 10752 B
#pragma unroll
  for (int reg = 0; reg < 4; ++reg) {
    int s = quad * 4 + reg;
    float h = hp[reg];
    last_hid[(long)(blk * 16 + s) * Hn + j0 + jl] = h;
    hs_f[s * 132 + j0 + jl] = h;
  }
  __syncthreads();

  // p1[n][k] = h[n]·W1[k] + b1[k] ; p2[n][k] = h[n]·W2[k]
  {
    int k = tid & 63;
    int part = (tid >> 6) & 1;
    int sg = tid >> 7;                    // 0..3 -> rows sg*4..sg*4+3
    const float* Wp = part ? W2 : W1;
    float a[4];
    float init = part ? 0.f : b1[k];
    a[0] = a[1] = a[2] = a[3] = init;
    for (int h = 0; h < 128; h += 4) {
      float4 w = *(const float4*)&Wp[k * 128 + h];
#pragma unroll
      for (int rr = 0; rr < 4; ++rr) {
        float4 q = *(const float4*)&hs_f[(sg * 4 + rr) * 132 + h];
        a[rr] += q.x * w.x + q.y * w.y + q.z * w.z + q.w * w.w;
      }
    }
    float* outp = part ? p2 : p1;
#pragma unroll
    for (int rr = 0; rr < 4; ++rr)
      outp[(long)(blk * 16 + sg * 4 + rr) * 64 + k] = a[rr];
  }
}

// ---------------- fused conv + t1: r_l stays in LDS ----------------
__global__ __launch_bounds__(128) void conv_t1_kernel(
    const float* __restrict__ X, const float* __restrict__ conv_w,
    const float* __restrict__ conv_b, const float* __restrict__ convl_w,
    const float* __restrict__ convl_b, const float* __restrict__ gc1_W,
    float* __restrict__ t1) {
  int tid = threadIdx.x;
  int n0 = blockIdx.x * 8;
  int b = n0 >> 9, m0 = n0 & 511;
  __shared__ float xs[8][16][20];
  __shared__ float cw[3200];
  __shared__ float clw[1600];
  __shared__ float rs[8][32];
  for (int idx = tid; idx < 3200; idx += 128) cw[idx] = conv_w[idx];
  for (int idx = tid; idx < 1600; idx += 128) clw[idx] = convl_w[idx];
  for (int w = 0; w < 20; ++w)
    xs[tid >> 4][tid & 15][w] = X[((long)(b * 20 + w) * 512 + m0) * 16 + tid];
  __syncthreads();
  if (tid < 80) {
    int s = tid / 10, k = tid % 10;
    float a0 = conv_b[k];
    float l0 = convl_b[k], l1 = convl_b[k];
    for (int f = 0; f < 16; ++f) {
#pragma unroll
      for (int w = 0; w < 20; ++w) a0 = fmaf(xs[s][f][w], cw[k * 320 + f * 20 + w], a0);
#pragma unroll
      for (int q = 0; q < 10; ++q) {
        float wv = clw[k * 160 + f * 10 + q];
        l0 = fmaf(xs[s][f][2 * q], wv, l0);
        l1 = fmaf(xs[s][f][2 * q + 1], wv, l1);
      }
    }
    rs[s][k * 3 + 0] = reluf_(a0);
    rs[s][k * 3 + 1] = reluf_(l0);
    rs[s][k * 3 + 2] = reluf_(l1);
  }
  __syncthreads();
  // t1[n][h] = sum_q rs[n][q] * gc1_W[q][h]; thread = h col
  float w[30];
#pragma unroll
  for (int q = 0; q < 30; ++q) w[q] = gc1_W[q * 128 + tid];
#pragma unroll
  for (int s = 0; s < 8; ++s) {
    float a = 0.f;
#pragma unroll
    for (int q = 0; q < 30; ++q) a = fmaf(rs[s][q], w[q], a);
    t1[(long)(n0 + s) * 128 + tid] = a;
  }
}

// ---------------- a_mx raw (32x32 tile) + fused column sum-of-squares ----------------
__global__ __launch_bounds__(256) void amx_kernel(
    const float* __restrict__ p1, const float* __restrict__ p2,
    const float* __restrict__ V, const float* __restrict__ bv,
    float* __restrict__ amx, float* __restrict__ ssq) {
  int tid = threadIdx.x;
  int j0 = blockIdx.x * 32, i0 = blockIdx.y * 32, bz = blockIdx.z;
  __shared__ float p1s[32][68];
  __shared__ float p2s[32][68];
  __shared__ float Vs[64];
  __shared__ float cred[16][33];
  if (tid < 64) Vs[tid] = V[tid];
  {
    int rr = tid >> 3, c0 = (tid & 7) * 8;
    *(float4*)&p1s[rr][c0]     = *(const float4*)&p1[(long)(bz * 512 + j0 + rr) * 64 + c0];
    *(float4*)&p1s[rr][c0 + 4] = *(const float4*)&p1[(long)(bz * 512 + j0 + rr) * 64 + c0 + 4];
    *(float4*)&p2s[rr][c0]     = *(const float4*)&p2[(long)(bz * 512 + i0 + rr) * 64 + c0];
    *(float4*)&p2s[rr][c0 + 4] = *(const float4*)&p2[(long)(bz * 512 + i0 + rr) * 64 + c0 + 4];
  }
  __syncthreads();
  int r0 = tid >> 4, c0 = tid & 15;     // rows r0,r0+16 ; cols c0,c0+16
  float acc[2][2] = {{0.f, 0.f}, {0.f, 0.f}};
  for (int k = 0; k < 64; ++k) {
    float vj0 = p1s[c0][k], vj1 = p1s[c0 + 16][k];
    float vi0 = p2s[r0][k], vi1 = p2s[r0 + 16][k];
    float vk = Vs[k];
    acc[0][0] = fmaf(eluf_(vj0 + vi0), vk, acc[0][0]);
    acc[0][1] = fmaf(eluf_(vj1 + vi0), vk, acc[0][1]);
    acc[1][0] = fmaf(eluf_(vj0 + vi1), vk, acc[1][0]);
    acc[1][1] = fmaf(eluf_(vj1 + vi1), vk, acc[1][1]);
  }
  float bvv = bv[0];
  float s2[2] = {0.f, 0.f};
#pragma unroll
  for (int a = 0; a < 2; ++a)
#pragma unroll
    for (int c = 0; c < 2; ++c) {
      float v = acc[a][c] + bvv;
      amx[((long)(bz * 512 + i0 + r0 + a * 16)) * 512 + j0 + c0 + c * 16] = v;
      s2[c] += v * v;
    }
  cred[r0][c0] = s2[0];
  cred[r0][c0 + 16] = s2[1];
  __syncthreads();
  if (tid < 32) {
    float s = 0.f;
#pragma unroll
    for (int p = 0; p < 16; ++p) s += cred[p][tid];
    atomicAdd(&ssq[bz * 512 + j0 + tid], s);
  }
}

// ---- gemm: c = sigmoid((amx/nrm)@Wb + wb); A = adj*c + (amx/nrm)*(1-c) ----
// nrm = max(sqrt(ssq),1e-12) folded into tile loads / epilogue.
__global__ __launch_bounds__(256) void gemm_cA(
    const float* __restrict__ amx, const float* __restrict__ Wb,
    const float* __restrict__ adj, const float* __restrict__ wb,
    const float* __restrict__ ssq, float* __restrict__ A) {
  const int bz = blockIdx.z;
  const int i0 = blockIdx.y * 64;
  const int j0 = blockIdx.x * 64;
  const int tid = threadIdx.x;
  const int ti = tid >> 4, tj = tid & 15;
  __shared__ float As[16][64];
  __shared__ float Bs[16][64];
  float acc[4][4] = {};
  const float* Abase = amx + (long)bz * 512 * 512;
  const float* sbase = ssq + bz * 512;
  for (int kk0 = 0; kk0 < 512; kk0 += 16) {
    __syncthreads();
    {
      int il = tid >> 2, kq = (tid & 3) * 4;
      float4 v = *(const float4*)&Abase[(long)(i0 + il) * 512 + kk0 + kq];
      float4 sq = *(const float4*)&sbase[kk0 + kq];
      As[kq + 0][il] = v.x / fmaxf(sqrtf(sq.x), 1e-12f);
      As[kq + 1][il] = v.y / fmaxf(sqrtf(sq.y), 1e-12f);
      As[kq + 2][il] = v.z / fmaxf(sqrtf(sq.z), 1e-12f);
      As[kq + 3][il] = v.w / fmaxf(sqrtf(sq.w), 1e-12f);
      int kk = tid >> 4, jl = (tid & 15) * 4;
      *(float4*)&Bs[kk][jl] = *(const float4*)&Wb[(long)(kk0 + kk) * 512 + j0 + jl];
    }
    __syncthreads();
#pragma unroll
    for (int k = 0; k < 16; ++k) {
      float4 a4 = *(const float4*)&As[k][ti * 4];
      float4 b4 = *(const float4*)&Bs[k][tj * 4];
      float av[4] = {a4.x, a4.y, a4.z, a4.w};
      float bw[4] = {b4.x, b4.y, b4.z, b4.w};
#pragma unroll
      for (int a = 0; a < 4; ++a)
#pragma unroll
        for (int c = 0; c < 4; ++c) acc[a][c] = fmaf(av[a], bw[c], acc[a][c]);
    }
  }
  const float wbv = wb[0];
  float4 sq4 = *(const float4*)&sbase[j0 + tj * 4];
  float4 sj;
  sj.x = 1.f / fmaxf(sqrtf(sq4.x), 1e-12f);
  sj.y = 1.f / fmaxf(sqrtf(sq4.y), 1e-12f);
  sj.z = 1.f / fmaxf(sqrtf(sq4.z), 1e-12f);
  sj.w = 1.f / fmaxf(sqrtf(sq4.w), 1e-12f);
#pragma unroll
  for (int a = 0; a < 4; ++a) {
    int i = i0 + ti * 4 + a;
    long idx4 = (long)bz * 512 * 512 + (long)i * 512 + j0 + tj * 4;
    float4 am = *(const float4*)&amx[idx4];
    am.x *= sj.x; am.y *= sj.y; am.z *= sj.z; am.w *= sj.w;
    float4 ad = *(const float4*)&adj[(long)i * 512 + j0 + tj * 4];
    float4 o;
    float c0 = sigmoidf_(acc[a][0] + wbv);
    float c1 = sigmoidf_(acc[a][1] + wbv);
    float c2 = sigmoidf_(acc[a][2] + wbv);
    float c3 = sigmoidf_(acc[a][3] + wbv);
    o.x = ad.x * c0 + am.x * (1.f - c0);
    o.y = ad.y * c1 + am.y * (1.f - c1);
    o.z = ad.z * c2 + am.z * (1.f - c2);
    o.w = ad.w * c3 + am.w * (1.f - c3);
    *(float4*)&A[idx4] = o;
  }
}

// ---------------- gemm_h1 (32x128 tile) + fused t2 = h1 @ gc2_W ----------------
// h1 never hits global memory.
__global__ __launch_bounds__(256) void gemm_h1t2(
    const float* __restrict__ A, const float* __restrict__ t1,
    const float* __restrict__ gc1_b, const float* __restrict__ gc2_W,
    float* __restrict__ t2) {
  const int bz = blockIdx.y;
  const int i0 = blockIdx.x * 32;
  const int tid = threadIdx.x;
  const int ti = tid >> 4, tj = tid & 15;   // rows ti*2+{0,1}, cols tj*8..+7
  __shared__ float As[16][32];
  __shared__ float Bs[16][132];
  __shared__ float h1s[32][132];
  float acc[2][8] = {};
  const float* Ab = A + (long)bz * 512 * 512;
  const float* Bb = t1 + (long)bz * 512 * 128;
  for (int kk0 = 0; kk0 < 512; kk0 += 16) {
    __syncthreads();
    {
      int il = tid >> 3, kq = (tid & 7) * 2;
      float2 v = *(const float2*)&Ab[(long)(i0 + il) * 512 + kk0 + kq];
      As[kq][il] = v.x;
      As[kq + 1][il] = v.y;
      int kk = tid >> 4, c0 = (tid & 15) * 8;
      *(float4*)&Bs[kk][c0]     = *(const float4*)&Bb[(long)(kk0 + kk) * 128 + c0];
      *(float4*)&Bs[kk][c0 + 4] = *(const float4*)&Bb[(long)(kk0 + kk) * 128 + c0 + 4];
    }
    __syncthreads();
#pragma unroll
    for (int k = 0; k < 16; ++k) {
      float a0 = As[k][ti * 2], a1 = As[k][ti * 2 + 1];
      float4 b0 = *(const float4*)&Bs[k][tj * 8];
      float4 b1 = *(const float4*)&Bs[k][tj * 8 + 4];
      acc[0][0] = fmaf(a0, b0.x, acc[0][0]);
      acc[0][1] = fmaf(a0, b0.y, acc[0][1]);
      acc[0][2] = fmaf(a0, b0.z, acc[0][2]);
      acc[0][3] = fmaf(a0, b0.w, acc[0][3]);
      acc[0][4] = fmaf(a0, b1.x, acc[0][4]);
      acc[0][5] = fmaf(a0, b1.y, acc[0][5]);
      acc[0][6] = fmaf(a0, b1.z, acc[0][6]);
      acc[0][7] = fmaf(a0, b1.w, acc[0][7]);
      acc[1][0] = fmaf(a1, b0.x, acc[1][0]);
      acc[1][1] = fmaf(a1, b0.y, acc[1][1]);
      acc[1][2] = fmaf(a1, b0.z, acc[1][2]);
      acc[1][3] = fmaf(a1, b0.w, acc[1][3]);
      acc[1][4] = fmaf(a1, b1.x, acc[1][4]);
      acc[1][5] = fmaf(a1, b1.y, acc[1][5]);
      acc[1][6] = fmaf(a1, b1.z, acc[1][6]);
      acc[1][7] = fmaf(a1, b1.w, acc[1][7]);
    }
  }
  // relu + bias -> LDS h1 tile
#pragma unroll
  for (int r = 0; r < 2; ++r)
#pragma unroll
    for (int c = 0; c < 8; ++c) {
      int col = tj * 8 + c;
      h1s[ti * 2 + r][col] = reluf_(acc[r][c] + gc1_b[col]);
    }
  __syncthreads();
  // t2[r][c] = sum_k h1s[r][k] * gc2_W[k][c]
  if (tid < 160) {
    int r = tid / 5, c2 = (tid % 5) * 2;
    float a0 = 0.f, a1 = 0.f;
    for (int k = 0; k < 128; ++k) {
      float h = h1s[r][k];
      a0 = fmaf(h, gc2_W[k * 10 + c2], a0);
      a1 = fmaf(h, gc2_W[k * 10 + c2 + 1], a1);
    }
    t2[((long)bz * 512 + i0 + r) * 10 + c2] = a0;
    t2[((long)bz * 512 + i0 + r) * 10 + c2 + 1] = a1;
  }
}

// ---------------- out_spatial = relu(A @ t2 + b2) fused with readout + BCE ----------------
__global__ __launch_bounds__(256) void spat_readout(
    const float* __restrict__ A, const float* __restrict__ t2,
    const float* __restrict__ gc2_b, const float* __restrict__ last_hid,
    const float* __restrict__ out_W, const float* __restrict__ out_b,
    const float* __restrict__ Y, float* __restrict__ d_out) {
  int tid = threadIdx.x;
  int bz = blockIdx.y;
  int i0 = blockIdx.x * 64;
  __shared__ float t2s[5120];
  __shared__ float As[64 * 33];
  __shared__ float osps[64][12];
  __shared__ float wS[138];
  for (int idx = tid; idx < 5120; idx += 256) t2s[idx] = t2[(long)bz * 5120 + idx];
  for (int idx = tid; idx < 138; idx += 256) wS[idx] = out_W[idx];
  int il = tid >> 2, cg = tid & 3;
  float a0 = 0.f, a1 = 0.f, a2 = 0.f;
  const float* Ab = A + (long)bz * 512 * 512;
  for (int kk0 = 0; kk0 < 512; kk0 += 32) {
    __syncthreads();
    for (int idx = tid; idx < 2048; idx += 256) {
      int r = idx >> 5, k = idx & 31;
      As[r * 33 + k] = Ab[(long)(i0 + r) * 512 + kk0 + k];
    }
    __syncthreads();
#pragma unroll 4
    for (int kk = 0; kk < 32; ++kk) {
      float av = As[il * 33 + kk];
      const float* tp = &t2s[(kk0 + kk) * 10];
      a0 = fmaf(av, tp[cg], a0);
      a1 = fmaf(av, tp[cg + 4], a1);
      if (cg < 2) a2 = fmaf(av, tp[cg + 8], a2);
    }
  }
  osps[il][cg]     = reluf_(a0 + gc2_b[cg]);
  osps[il][cg + 4] = reluf_(a1 + gc2_b[cg + 4]);
  if (cg < 2) osps[il][cg + 8] = reluf_(a2 + gc2_b[cg + 8]);
  __syncthreads();
  if (tid < 64) {
    int gid = bz * 512 + i0 + tid;
    float y = out_b[0];
#pragma unroll
    for (int k = 0; k < 10; ++k) y = fmaf(osps[tid][k], wS[k], y);
    const float* hp = &last_hid[(long)gid * 128];
    for (int h = 0; h < 128; h += 4) {
      float4 hv = *(const float4*)&hp[h];
      y = fmaf(hv.x, wS[10 + h + 0], y);
      y = fmaf(hv.y, wS[10 + h + 1], y);
      y = fmaf(hv.z, wS[10 + h + 2], y);
      y = fmaf(hv.w, wS[10 + h + 3], y);
    }
    d_out[1 + gid] = sigmoidf_(y);
    float l = fmaxf(y, 0.f) + log1pf(__expf(-fabsf(y))) - Y[gid] * y;
#pragma unroll
    for (int off = 32; off > 0; off >>= 1) l += __shfl_down(l, off);
    if (tid == 0) atomicAdd(d_out, l * (1.0f / 4096.f));
  }
}

// ---------------- launcher ----------------
extern "C" void kernel_launch(void* const* d_in, const int* in_sizes, int n_in,
                              void* d_out, int out_size, void* d_ws, size_t ws_size,
                              hipStream_t stream) {
  const float* X       = (const float*)d_in[0];
  const float* Y       = (const float*)d_in[1];
  const float* adj     = (const float*)d_in[2];
  const float* V       = (const float*)d_in[3];
  const float* bv      = (const float*)d_in[4];
  const float* W1      = (const float*)d_in[5];
  const float* b1      = (const float*)d_in[6];
  const float* W2      = (const float*)d_in[7];
  const float* Wb      = (const float*)d_in[8];
  const float* wb      = (const float*)d_in[9];
  const float* conv_w  = (const float*)d_in[10];
  const float* conv_b  = (const float*)d_in[11];
  const float* convl_w = (const float*)d_in[12];
  const float* convl_b = (const float*)d_in[13];
  const float* gWih    = (const float*)d_in[14];
  const float* gWhh    = (const float*)d_in[15];
  const float* gbih    = (const float*)d_in[16];
  const float* gbhh    = (const float*)d_in[17];
  const float* gc1_W   = (const float*)d_in[18];
  const float* gc1_b   = (const float*)d_in[19];
  const float* gc2_W   = (const float*)d_in[20];
  const float* gc2_b   = (const float*)d_in[21];
  const float* out_W   = (const float*)d_in[22];
  const float* out_b   = (const float*)d_in[23];
  float* out = (float*)d_out;

  float* ws = (float*)d_ws;
  float* lhid  = ws; ws += 524288;
  float* p1    = ws; ws += 262144;
  float* p2    = ws; ws += 262144;
  float* amx   = ws; ws += 2097152;
  float* ssq   = ws; ws += 4096;
  float* t1    = ws; ws += 524288;
  float* Abuf  = ws; ws += 2097152;
  float* t2    = ws; ws += 40960;
  float* Bpk   = ws; ws += 122880;   // 245760 shorts
  if (ws_size < (size_t)(ws - (float*)d_ws) * sizeof(float)) return;
  unsigned short* Bpack = (unsigned short*)Bpk;

  pack_kernel<<<240, 256, 0, stream>>>(gWhh, gWih, Bpack, ssq, out);
  gru_kernel<<<256, 512, 0, stream>>>(X, Bpack, gbih, gbhh, W1, W2, b1,
                                      lhid, p1, p2);
  conv_t1_kernel<<<512, 128, 0, stream>>>(X, conv_w, conv_b, convl_w, convl_b,
                                          gc1_W, t1);
  amx_kernel<<<dim3(16, 16, 8), 256, 0, stream>>>(p1, p2, V, bv, amx, ssq);
  gemm_cA<<<dim3(8, 8, 8), 256, 0, stream>>>(amx, Wb, adj, wb, ssq, Abuf);
  gemm_h1t2<<<dim3(16, 8), 256, 0, stream>>>(Abuf, t1, gc1_b, gc2_W, t2);
  spat_readout<<<dim3(8, 8), 256, 0, stream>>>(Abuf, t2, gc2_b, lhid,
                                               out_W, out_b, Y, out);
}

// Round 5
// 268.397 us; speedup vs baseline: 2.1999x; 1.2667x over previous
//
#include <hip/hip_runtime.h>
#include <math.h>

// ---------------- sizes ----------------
#define Bn 8
#define Wn 20
#define Mn 512
#define Fn 16
#define Hn 128
#define HALFn 64
#define Kn 10

typedef __attribute__((ext_vector_type(8))) short short8;
typedef __attribute__((ext_vector_type(4))) float f32x4;
typedef unsigned short ushort_t;

__device__ __forceinline__ float sigmoidf_(float x) {
  return 1.0f / (1.0f + __expf(-x));
}
__device__ __forceinline__ float tanhf_(float x) {
  float xx = fminf(fmaxf(x, -15.f), 15.f);
  float e = __expf(2.f * xx);
  return (e - 1.f) / (e + 1.f);
}
__device__ __forceinline__ float reluf_(float x) { return fmaxf(x, 0.f); }
__device__ __forceinline__ float eluf_(float x) {
  return (x > 0.f) ? x : (__expf(x) - 1.f);
}
__device__ __forceinline__ ushort_t bf16_rne(float v) {
  unsigned u = __float_as_uint(v);
  u += 0x7FFFu + ((u >> 16) & 1u);
  return (ushort_t)(u >> 16);
}
__device__ __forceinline__ float bf16_to_f(ushort_t b) {
  return __uint_as_float(((unsigned)b) << 16);
}

// ---------------- prep: GRU weight pack + Wb transpose/split + zero init ----
// blocks 0..239: Bpack for GRU (as before) + zero ssq/d_out.
// blocks 240..303: WbT_hi/lo[j][k] = split(Wb[k][j]) via LDS 64x64 tile transpose.
__global__ __launch_bounds__(256) void pack_kernel(
    const float* __restrict__ Whh, const float* __restrict__ Wih,
    const float* __restrict__ Wb, ushort_t* __restrict__ Bpack,
    ushort_t* __restrict__ WbT_hi, ushort_t* __restrict__ WbT_lo,
    float* __restrict__ ssq, float* __restrict__ d_out) {
  int tid = threadIdx.x;
  if (blockIdx.x < 240) {
    int idx = blockIdx.x * 256 + tid;   // 24*5*512 = 61440
    if (idx < 4096) ssq[idx] = 0.f;
    if (idx == 0) d_out[0] = 0.f;
    if (idx >= 24 * 5 * 512) return;
    int j = idx & 7;
    int lane = (idx >> 3) & 63;
    int ks = (idx >> 9) % 5;
    int nt = idx / (5 * 512);
    int k = ks * 32 + (lane >> 4) * 8 + j;
    int g = (nt & 7) * 16 + (nt >> 3) * 128 + (lane & 15);
    float val = 0.f;
    if (k < 128) val = Whh[g * 128 + k];
    else if (k < 144) val = Wih[g * 16 + (k - 128)];
    ushort_t hb = bf16_rne(val);
    float lo = val - bf16_to_f(hb);
    Bpack[(((long)nt * 5 + ks) * 2 + 0) * 512 + lane * 8 + j] = hb;
    Bpack[(((long)nt * 5 + ks) * 2 + 1) * 512 + lane * 8 + j] = bf16_rne(lo);
  } else {
    int t = blockIdx.x - 240;           // 0..63
    int k0 = (t >> 3) * 64, j0 = (t & 7) * 64;
    __shared__ float wt[64][65];
    for (int idx = tid; idx < 4096; idx += 256) {
      int r = idx >> 6, c = idx & 63;
      wt[r][c] = Wb[(long)(k0 + r) * 512 + j0 + c];
    }
    __syncthreads();
    for (int idx = tid; idx < 4096; idx += 256) {
      int r = idx >> 6, c = idx & 63;     // output row j0+r, col k0+c
      float v = wt[c][r];
      ushort_t hb = bf16_rne(v);
      WbT_hi[(long)(j0 + r) * 512 + k0 + c] = hb;
      WbT_lo[(long)(j0 + r) * 512 + k0 + c] = bf16_rne(v - bf16_to_f(hb));
    }
  }
}

// ---------------- GRU via split-bf16 MFMA + fused attn-projection epilogue ----
#define LDK 168
__global__ __launch_bounds__(512, 2) void gru_kernel(
    const float* __restrict__ X, const ushort_t* __restrict__ Bpack,
    const float* __restrict__ bih, const float* __restrict__ bhh,
    const float* __restrict__ W1, const float* __restrict__ W2,
    const float* __restrict__ b1, float* __restrict__ last_hid,
    float* __restrict__ p1, float* __restrict__ p2) {
  const int tid = threadIdx.x;
  const int wave = tid >> 6;
  const int lane = tid & 63;
  const int quad = lane >> 4;
  const int jl = lane & 15;
  const int j0 = wave * 16;
  const int blk = blockIdx.x;
  const int b = blk >> 5;
  const int m0 = (blk & 31) * 16;

  __shared__ __align__(16) ushort_t smem_hs[2 * 16 * LDK];
  ushort_t* h_hi = smem_hs;
  ushort_t* h_lo = smem_hs + 16 * LDK;

  short8 frR[5][2], frZ[5][2], frN[4][2], frXN[2];
#pragma unroll
  for (int ks = 0; ks < 5; ++ks) {
#pragma unroll
    for (int p = 0; p < 2; ++p) {
      frR[ks][p] = *(const short8*)&Bpack[(((long)(wave) * 5 + ks) * 2 + p) * 512 + lane * 8];
      frZ[ks][p] = *(const short8*)&Bpack[(((long)(8 + wave) * 5 + ks) * 2 + p) * 512 + lane * 8];
    }
  }
#pragma unroll
  for (int ks = 0; ks < 4; ++ks) {
#pragma unroll
    for (int p = 0; p < 2; ++p)
      frN[ks][p] = *(const short8*)&Bpack[(((long)(16 + wave) * 5 + ks) * 2 + p) * 512 + lane * 8];
  }
#pragma unroll
  for (int p = 0; p < 2; ++p)
    frXN[p] = *(const short8*)&Bpack[(((long)(16 + wave) * 5 + 4) * 2 + p) * 512 + lane * 8];

  const float cr  = bih[j0 + jl] + bhh[j0 + jl];
  const float cz  = bih[128 + j0 + jl] + bhh[128 + j0 + jl];
  const float cnx = bih[256 + j0 + jl];
  const float cnh = bhh[256 + j0 + jl];

  for (int i = tid; i < 16 * LDK; i += 512) { h_hi[i] = 0; h_lo[i] = 0; }

  const float* Xb = X + (long)b * (Wn * Mn * Fn) + (long)m0 * Fn;
  float x0 = 0.f;
  if (tid < 256) x0 = Xb[tid];
  __syncthreads();
  if (tid < 256) {
    int s = tid >> 4, f = tid & 15;
    ushort_t hb = bf16_rne(x0);
    h_hi[s * LDK + 128 + f] = hb;
    h_lo[s * LDK + 128 + f] = bf16_rne(x0 - bf16_to_f(hb));
  }
  __syncthreads();

  float hp[4] = {0.f, 0.f, 0.f, 0.f};

  for (int t = 0; t < Wn; ++t) {
    float xpre = 0.f;
    {
      int tt = (t < Wn - 1) ? (t + 1) : (Wn - 1);
      if (tid < 256) xpre = Xb[(long)tt * (Mn * Fn) + tid];
    }
    f32x4 aR = {0.f, 0.f, 0.f, 0.f}, aZ = {0.f, 0.f, 0.f, 0.f};
    f32x4 aHN = {0.f, 0.f, 0.f, 0.f}, aXN = {0.f, 0.f, 0.f, 0.f};
#pragma unroll
    for (int ks = 0; ks < 5; ++ks) {
      short8 ah = *(const short8*)&h_hi[jl * LDK + ks * 32 + quad * 8];
      short8 al = *(const short8*)&h_lo[jl * LDK + ks * 32 + quad * 8];
      aR = __builtin_amdgcn_mfma_f32_16x16x32_bf16(ah, frR[ks][0], aR, 0, 0, 0);
      aR = __builtin_amdgcn_mfma_f32_16x16x32_bf16(ah, frR[ks][1], aR, 0, 0, 0);
      aR = __builtin_amdgcn_mfma_f32_16x16x32_bf16(al, frR[ks][0], aR, 0, 0, 0);
      aZ = __builtin_amdgcn_mfma_f32_16x16x32_bf16(ah, frZ[ks][0], aZ, 0, 0, 0);
      aZ = __builtin_amdgcn_mfma_f32_16x16x32_bf16(ah, frZ[ks][1], aZ, 0, 0, 0);
      aZ = __builtin_amdgcn_mfma_f32_16x16x32_bf16(al, frZ[ks][0], aZ, 0, 0, 0);
      if (ks < 4) {
        aHN = __builtin_amdgcn_mfma_f32_16x16x32_bf16(ah, frN[ks][0], aHN, 0, 0, 0);
        aHN = __builtin_amdgcn_mfma_f32_16x16x32_bf16(ah, frN[ks][1], aHN, 0, 0, 0);
        aHN = __builtin_amdgcn_mfma_f32_16x16x32_bf16(al, frN[ks][0], aHN, 0, 0, 0);
      } else {
        aXN = __builtin_amdgcn_mfma_f32_16x16x32_bf16(ah, frXN[0], aXN, 0, 0, 0);
        aXN = __builtin_amdgcn_mfma_f32_16x16x32_bf16(ah, frXN[1], aXN, 0, 0, 0);
        aXN = __builtin_amdgcn_mfma_f32_16x16x32_bf16(al, frXN[0], aXN, 0, 0, 0);
      }
    }
    __syncthreads();
#pragma unroll
    for (int reg = 0; reg < 4; ++reg) {
      float r = sigmoidf_(aR[reg] + cr);
      float z = sigmoidf_(aZ[reg] + cz);
      float n = tanhf_(aXN[reg] + cnx + r * (aHN[reg] + cnh));
      float h = (1.f - z) * n + z * hp[reg];
      hp[reg] = h;
      int s = quad * 4 + reg;
      ushort_t hb = bf16_rne(h);
      h_hi[s * LDK + j0 + jl] = hb;
      h_lo[s * LDK + j0 + jl] = bf16_rne(h - bf16_to_f(hb));
    }
    if (tid < 256 && t < Wn - 1) {
      int s = tid >> 4, f = tid & 15;
      ushort_t hb = bf16_rne(xpre);
      h_hi[s * LDK + 128 + f] = hb;
      h_lo[s * LDK + 128 + f] = bf16_rne(xpre - bf16_to_f(hb));
    }
    __syncthreads();
  }

  float* hs_f = (float*)smem_hs;          // 16 x 132 floats
#pragma unroll
  for (int reg = 0; reg < 4; ++reg) {
    int s = quad * 4 + reg;
    float h = hp[reg];
    last_hid[(long)(blk * 16 + s) * Hn + j0 + jl] = h;
    hs_f[s * 132 + j0 + jl] = h;
  }
  __syncthreads();
  {
    int k = tid & 63;
    int part = (tid >> 6) & 1;
    int sg = tid >> 7;
    const float* Wp = part ? W2 : W1;
    float a[4];
    float init = part ? 0.f : b1[k];
    a[0] = a[1] = a[2] = a[3] = init;
    for (int h = 0; h < 128; h += 4) {
      float4 w = *(const float4*)&Wp[k * 128 + h];
#pragma unroll
      for (int rr = 0; rr < 4; ++rr) {
        float4 q = *(const float4*)&hs_f[(sg * 4 + rr) * 132 + h];
        a[rr] += q.x * w.x + q.y * w.y + q.z * w.z + q.w * w.w;
      }
    }
    float* outp = part ? p2 : p1;
#pragma unroll
    for (int rr = 0; rr < 4; ++rr)
      outp[(long)(blk * 16 + sg * 4 + rr) * 64 + k] = a[rr];
  }
}

// ---------------- fused conv + t1; t1 emitted as bf16 hi/lo TRANSPOSED [h][m] ----
__global__ __launch_bounds__(128) void conv_t1_kernel(
    const float* __restrict__ X, const float* __restrict__ conv_w,
    const float* __restrict__ conv_b, const float* __restrict__ convl_w,
    const float* __restrict__ convl_b, const float* __restrict__ gc1_W,
    ushort_t* __restrict__ t1T_hi, ushort_t* __restrict__ t1T_lo) {
  int tid = threadIdx.x;
  int n0 = blockIdx.x * 8;
  int b = n0 >> 9, m0 = n0 & 511;
  __shared__ float xs[8][16][20];
  __shared__ float cw[3200];
  __shared__ float clw[1600];
  __shared__ float rs[8][32];
  for (int idx = tid; idx < 3200; idx += 128) cw[idx] = conv_w[idx];
  for (int idx = tid; idx < 1600; idx += 128) clw[idx] = convl_w[idx];
  for (int w = 0; w < 20; ++w)
    xs[tid >> 4][tid & 15][w] = X[((long)(b * 20 + w) * 512 + m0) * 16 + tid];
  __syncthreads();
  if (tid < 80) {
    int s = tid / 10, k = tid % 10;
    float a0 = conv_b[k];
    float l0 = convl_b[k], l1 = convl_b[k];
    for (int f = 0; f < 16; ++f) {
#pragma unroll
      for (int w = 0; w < 20; ++w) a0 = fmaf(xs[s][f][w], cw[k * 320 + f * 20 + w], a0);
#pragma unroll
      for (int q = 0; q < 10; ++q) {
        float wv = clw[k * 160 + f * 10 + q];
        l0 = fmaf(xs[s][f][2 * q], wv, l0);
        l1 = fmaf(xs[s][f][2 * q + 1], wv, l1);
      }
    }
    rs[s][k * 3 + 0] = reluf_(a0);
    rs[s][k * 3 + 1] = reluf_(l0);
    rs[s][k * 3 + 2] = reluf_(l1);
  }
  __syncthreads();
  float w[30];
#pragma unroll
  for (int q = 0; q < 30; ++q) w[q] = gc1_W[q * 128 + tid];
  long base = ((long)b * 128 + tid) * 512 + m0;
#pragma unroll
  for (int s = 0; s < 8; ++s) {
    float a = 0.f;
#pragma unroll
    for (int q = 0; q < 30; ++q) a = fmaf(rs[s][q], w[q], a);
    ushort_t hb = bf16_rne(a);
    t1T_hi[base + s] = hb;
    t1T_lo[base + s] = bf16_rne(a - bf16_to_f(hb));
  }
}

// ---------------- a_mx raw (32x32 tile) + fused column sum-of-squares ----------------
__global__ __launch_bounds__(256) void amx_kernel(
    const float* __restrict__ p1, const float* __restrict__ p2,
    const float* __restrict__ V, const float* __restrict__ bv,
    float* __restrict__ amx, float* __restrict__ ssq) {
  int tid = threadIdx.x;
  int j0 = blockIdx.x * 32, i0 = blockIdx.y * 32, bz = blockIdx.z;
  __shared__ float p1s[32][68];
  __shared__ float p2s[32][68];
  __shared__ float Vs[64];
  __shared__ float cred[16][33];
  if (tid < 64) Vs[tid] = V[tid];
  {
    int rr = tid >> 3, c0 = (tid & 7) * 8;
    *(float4*)&p1s[rr][c0]     = *(const float4*)&p1[(long)(bz * 512 + j0 + rr) * 64 + c0];
    *(float4*)&p1s[rr][c0 + 4] = *(const float4*)&p1[(long)(bz * 512 + j0 + rr) * 64 + c0 + 4];
    *(float4*)&p2s[rr][c0]     = *(const float4*)&p2[(long)(bz * 512 + i0 + rr) * 64 + c0];
    *(float4*)&p2s[rr][c0 + 4] = *(const float4*)&p2[(long)(bz * 512 + i0 + rr) * 64 + c0 + 4];
  }
  __syncthreads();
  int r0 = tid >> 4, c0 = tid & 15;
  float acc[2][2] = {{0.f, 0.f}, {0.f, 0.f}};
  for (int k = 0; k < 64; ++k) {
    float vj0 = p1s[c0][k], vj1 = p1s[c0 + 16][k];
    float vi0 = p2s[r0][k], vi1 = p2s[r0 + 16][k];
    float vk = Vs[k];
    acc[0][0] = fmaf(eluf_(vj0 + vi0), vk, acc[0][0]);
    acc[0][1] = fmaf(eluf_(vj1 + vi0), vk, acc[0][1]);
    acc[1][0] = fmaf(eluf_(vj0 + vi1), vk, acc[1][0]);
    acc[1][1] = fmaf(eluf_(vj1 + vi1), vk, acc[1][1]);
  }
  float bvv = bv[0];
  float s2[2] = {0.f, 0.f};
#pragma unroll
  for (int a = 0; a < 2; ++a)
#pragma unroll
    for (int c = 0; c < 2; ++c) {
      float v = acc[a][c] + bvv;
      amx[((long)(bz * 512 + i0 + r0 + a * 16)) * 512 + j0 + c0 + c * 16] = v;
      s2[c] += v * v;
    }
  cred[r0][c0] = s2[0];
  cred[r0][c0 + 16] = s2[1];
  __syncthreads();
  if (tid < 32) {
    float s = 0.f;
#pragma unroll
    for (int p = 0; p < 16; ++p) s += cred[p][tid];
    atomicAdd(&ssq[bz * 512 + j0 + tid], s);
  }
}

// ---- gemm_cA via split-bf16 MFMA ----
// C = sigmoid(Ahat@Wb + wb); A_out = adj*c + Ahat*(1-c), Ahat = amx col-scaled.
// BM=128, BN=64, BK=32; 128 threads = 2 waves, each 64x64 (4x4 MFMA tiles).
#define CPK 40
__global__ __launch_bounds__(128, 2) void gemm_cA(
    const float* __restrict__ amx, const ushort_t* __restrict__ WbT_hi,
    const ushort_t* __restrict__ WbT_lo, const float* __restrict__ adj,
    const float* __restrict__ wb, const float* __restrict__ ssq,
    float* __restrict__ A) {
  const int bz = blockIdx.z;
  const int i0 = blockIdx.y * 128;
  const int j0 = blockIdx.x * 64;
  const int tid = threadIdx.x;
  const int wave = tid >> 6;
  const int lane = tid & 63;
  const int quad = lane >> 4, jl = lane & 15;

  __shared__ __align__(16) ushort_t Ahi[128][CPK];
  __shared__ __align__(16) ushort_t Alo[128][CPK];
  __shared__ __align__(16) ushort_t Bhi[64][CPK];
  __shared__ __align__(16) ushort_t Blo[64][CPK];
  __shared__ float rs_s[512];

  const float* Abase = amx + (long)bz * 262144;
  const float* sb = ssq + bz * 512;
  for (int i = tid; i < 512; i += 128)
    rs_s[i] = 1.f / fmaxf(sqrtf(sb[i]), 1e-12f);

  f32x4 acc[4][4];
#pragma unroll
  for (int a = 0; a < 4; ++a)
#pragma unroll
    for (int c = 0; c < 4; ++c) acc[a][c] = (f32x4){0.f, 0.f, 0.f, 0.f};

  for (int kk0 = 0; kk0 < 512; kk0 += 32) {
    __syncthreads();
#pragma unroll
    for (int l = 0; l < 8; ++l) {
      int e = l * 512 + tid * 4;
      int r = e >> 5, kq = e & 31;
      float4 v = *(const float4*)&Abase[(long)(i0 + r) * 512 + kk0 + kq];
      float4 sc = *(const float4*)&rs_s[kk0 + kq];
      float vv[4] = {v.x * sc.x, v.y * sc.y, v.z * sc.z, v.w * sc.w};
#pragma unroll
      for (int q = 0; q < 4; ++q) {
        ushort_t hb = bf16_rne(vv[q]);
        Ahi[r][kq + q] = hb;
        Alo[r][kq + q] = bf16_rne(vv[q] - bf16_to_f(hb));
      }
    }
#pragma unroll
    for (int l = 0; l < 2; ++l) {
      int e = l * 1024 + tid * 8;
      int r = e >> 5, kc = e & 31;
      *(uint4*)&Bhi[r][kc] = *(const uint4*)&WbT_hi[(long)(j0 + r) * 512 + kk0 + kc];
      *(uint4*)&Blo[r][kc] = *(const uint4*)&WbT_lo[(long)(j0 + r) * 512 + kk0 + kc];
    }
    __syncthreads();
    short8 ah[4], al[4], bh[4], bl[4];
#pragma unroll
    for (int tm = 0; tm < 4; ++tm) {
      ah[tm] = *(const short8*)&Ahi[wave * 64 + tm * 16 + jl][quad * 8];
      al[tm] = *(const short8*)&Alo[wave * 64 + tm * 16 + jl][quad * 8];
    }
#pragma unroll
    for (int tn = 0; tn < 4; ++tn) {
      bh[tn] = *(const short8*)&Bhi[tn * 16 + jl][quad * 8];
      bl[tn] = *(const short8*)&Blo[tn * 16 + jl][quad * 8];
    }
#pragma unroll
    for (int tm = 0; tm < 4; ++tm)
#pragma unroll
      for (int tn = 0; tn < 4; ++tn) {
        acc[tm][tn] = __builtin_amdgcn_mfma_f32_16x16x32_bf16(ah[tm], bh[tn], acc[tm][tn], 0, 0, 0);
        acc[tm][tn] = __builtin_amdgcn_mfma_f32_16x16x32_bf16(ah[tm], bl[tn], acc[tm][tn], 0, 0, 0);
        acc[tm][tn] = __builtin_amdgcn_mfma_f32_16x16x32_bf16(al[tm], bh[tn], acc[tm][tn], 0, 0, 0);
      }
  }

  const float wbv = wb[0];
#pragma unroll
  for (int tn = 0; tn < 4; ++tn) {
    int j = j0 + tn * 16 + jl;
    float sj = rs_s[j];
#pragma unroll
    for (int tm = 0; tm < 4; ++tm) {
#pragma unroll
      for (int reg = 0; reg < 4; ++reg) {
        int i = i0 + wave * 64 + tm * 16 + quad * 4 + reg;
        long ofs = (long)bz * 262144 + (long)i * 512 + j;
        float c = sigmoidf_(acc[tm][tn][reg] + wbv);
        float am = Abase[(long)i * 512 + j] * sj;
        float ad = adj[(long)i * 512 + j];
        A[ofs] = ad * c + am * (1.f - c);
      }
    }
  }
}

// ---------------- gemm_h1 via split-bf16 MFMA + fused t2 = h1 @ gc2_W ----------------
// BM=32, BN=128, BK=32; 256 threads = 4 waves, wave w cols w*32 (2x2 tiles of 16).
__global__ __launch_bounds__(256, 2) void gemm_h1t2(
    const float* __restrict__ A, const ushort_t* __restrict__ t1T_hi,
    const ushort_t* __restrict__ t1T_lo, const float* __restrict__ gc1_b,
    const float* __restrict__ gc2_W, float* __restrict__ t2) {
  const int bz = blockIdx.y;
  const int i0 = blockIdx.x * 32;
  const int tid = threadIdx.x;
  const int wave = tid >> 6;
  const int lane = tid & 63;
  const int quad = lane >> 4, jl = lane & 15;

  __shared__ __align__(16) ushort_t Ahi[32][CPK];
  __shared__ __align__(16) ushort_t Alo[32][CPK];
  __shared__ __align__(16) ushort_t Bhi[128][CPK];
  __shared__ __align__(16) ushort_t Blo[128][CPK];
  __shared__ float h1s[32][132];
  __shared__ float gw[1280];

  const float* Ab = A + (long)bz * 262144;
  for (int idx = tid; idx < 1280; idx += 256) gw[idx] = gc2_W[idx];

  f32x4 acc[2][2];
#pragma unroll
  for (int a = 0; a < 2; ++a)
#pragma unroll
    for (int c = 0; c < 2; ++c) acc[a][c] = (f32x4){0.f, 0.f, 0.f, 0.f};

  for (int kk0 = 0; kk0 < 512; kk0 += 32) {
    __syncthreads();
    {
      int e = tid * 4;
      int r = e >> 5, kq = e & 31;
      float4 v = *(const float4*)&Ab[(long)(i0 + r) * 512 + kk0 + kq];
      float vv[4] = {v.x, v.y, v.z, v.w};
#pragma unroll
      for (int q = 0; q < 4; ++q) {
        ushort_t hb = bf16_rne(vv[q]);
        Ahi[r][kq + q] = hb;
        Alo[r][kq + q] = bf16_rne(vv[q] - bf16_to_f(hb));
      }
    }
#pragma unroll
    for (int l = 0; l < 2; ++l) {
      int e = l * 2048 + tid * 8;
      int r = e >> 5, kc = e & 31;
      *(uint4*)&Bhi[r][kc] = *(const uint4*)&t1T_hi[((long)bz * 128 + r) * 512 + kk0 + kc];
      *(uint4*)&Blo[r][kc] = *(const uint4*)&t1T_lo[((long)bz * 128 + r) * 512 + kk0 + kc];
    }
    __syncthreads();
    short8 ah[2], al[2], bh[2], bl[2];
#pragma unroll
    for (int tm = 0; tm < 2; ++tm) {
      ah[tm] = *(const short8*)&Ahi[tm * 16 + jl][quad * 8];
      al[tm] = *(const short8*)&Alo[tm * 16 + jl][quad * 8];
    }
#pragma unroll
    for (int tn = 0; tn < 2; ++tn) {
      bh[tn] = *(const short8*)&Bhi[wave * 32 + tn * 16 + jl][quad * 8];
      bl[tn] = *(const short8*)&Blo[wave * 32 + tn * 16 + jl][quad * 8];
    }
#pragma unroll
    for (int tm = 0; tm < 2; ++tm)
#pragma unroll
      for (int tn = 0; tn < 2; ++tn) {
        acc[tm][tn] = __builtin_amdgcn_mfma_f32_16x16x32_bf16(ah[tm], bh[tn], acc[tm][tn], 0, 0, 0);
        acc[tm][tn] = __builtin_amdgcn_mfma_f32_16x16x32_bf16(ah[tm], bl[tn], acc[tm][tn], 0, 0, 0);
        acc[tm][tn] = __builtin_amdgcn_mfma_f32_16x16x32_bf16(al[tm], bh[tn], acc[tm][tn], 0, 0, 0);
      }
  }
  __syncthreads();
#pragma unroll
  for (int tm = 0; tm < 2; ++tm)
#pragma unroll
    for (int tn = 0; tn < 2; ++tn) {
      int n = wave * 32 + tn * 16 + jl;
      float bb = gc1_b[n];
#pragma unroll
      for (int reg = 0; reg < 4; ++reg) {
        int r = tm * 16 + quad * 4 + reg;
        h1s[r][n] = reluf_(acc[tm][tn][reg] + bb);
      }
    }
  __syncthreads();
  for (int e = tid; e < 320; e += 256) {
    int r = e / 10, c = e % 10;
    float a = 0.f;
#pragma unroll 4
    for (int k = 0; k < 128; ++k) a = fmaf(h1s[r][k], gw[k * 10 + c], a);
    t2[((long)bz * 512 + i0 + r) * 10 + c] = a;
  }
}

// ---------------- out_spatial = relu(A @ t2 + b2) fused with readout + BCE ----------
// 16 rows/block, K split across 16 lanes/row, shuffle-reduced.
__global__ __launch_bounds__(256) void spat_readout(
    const float* __restrict__ A, const float* __restrict__ t2,
    const float* __restrict__ gc2_b, const float* __restrict__ last_hid,
    const float* __restrict__ out_W, const float* __restrict__ out_b,
    const float* __restrict__ Y, float* __restrict__ d_out) {
  int tid = threadIdx.x;
  int bz = blockIdx.y;
  int i0 = blockIdx.x * 16;
  __shared__ float t2s[5120];
  __shared__ float wS[138];
  __shared__ float osps[16][12];
  for (int idx = tid; idx < 5120; idx += 256) t2s[idx] = t2[(long)bz * 5120 + idx];
  for (int idx = tid; idx < 138; idx += 256) wS[idx] = out_W[idx];
  __syncthreads();
  int r = tid >> 4, sk = tid & 15;
  const float* Arow = A + (long)bz * 262144 + (long)(i0 + r) * 512;
  float acc[10] = {0, 0, 0, 0, 0, 0, 0, 0, 0, 0};
  for (int k = sk; k < 512; k += 16) {
    float av = Arow[k];
    const float* tp = &t2s[k * 10];
#pragma unroll
    for (int c = 0; c < 10; ++c) acc[c] = fmaf(av, tp[c], acc[c]);
  }
#pragma unroll
  for (int off = 8; off; off >>= 1)
#pragma unroll
    for (int c = 0; c < 10; ++c) acc[c] += __shfl_xor(acc[c], off);
  if (sk == 0) {
#pragma unroll
    for (int c = 0; c < 10; ++c) osps[r][c] = reluf_(acc[c] + gc2_b[c]);
  }
  __syncthreads();
  float l = 0.f;
  if (tid < 16) {
    int gid = bz * 512 + i0 + tid;
    float y = out_b[0];
#pragma unroll
    for (int k = 0; k < 10; ++k) y = fmaf(osps[tid][k], wS[k], y);
    const float* hp = &last_hid[(long)gid * 128];
    for (int h = 0; h < 128; h += 4) {
      float4 hv = *(const float4*)&hp[h];
      y = fmaf(hv.x, wS[10 + h + 0], y);
      y = fmaf(hv.y, wS[10 + h + 1], y);
      y = fmaf(hv.z, wS[10 + h + 2], y);
      y = fmaf(hv.w, wS[10 + h + 3], y);
    }
    d_out[1 + gid] = sigmoidf_(y);
    l = fmaxf(y, 0.f) + log1pf(__expf(-fabsf(y))) - Y[gid] * y;
  }
  if (tid < 64) {
#pragma unroll
    for (int off = 8; off; off >>= 1) l += __shfl_down(l, off);
    if (tid == 0) atomicAdd(d_out, l * (1.0f / 4096.f));
  }
}

// ---------------- launcher ----------------
extern "C" void kernel_launch(void* const* d_in, const int* in_sizes, int n_in,
                              void* d_out, int out_size, void* d_ws, size_t ws_size,
                              hipStream_t stream) {
  const float* X       = (const float*)d_in[0];
  const float* Y       = (const float*)d_in[1];
  const float* adj     = (const float*)d_in[2];
  const float* V       = (const float*)d_in[3];
  const float* bv      = (const float*)d_in[4];
  const float* W1      = (const float*)d_in[5];
  const float* b1      = (const float*)d_in[6];
  const float* W2      = (const float*)d_in[7];
  const float* Wb      = (const float*)d_in[8];
  const float* wb      = (const float*)d_in[9];
  const float* conv_w  = (const float*)d_in[10];
  const float* conv_b  = (const float*)d_in[11];
  const float* convl_w = (const float*)d_in[12];
  const float* convl_b = (const float*)d_in[13];
  const float* gWih    = (const float*)d_in[14];
  const float* gWhh    = (const float*)d_in[15];
  const float* gbih    = (const float*)d_in[16];
  const float* gbhh    = (const float*)d_in[17];
  const float* gc1_W   = (const float*)d_in[18];
  const float* gc1_b   = (const float*)d_in[19];
  const float* gc2_W   = (const float*)d_in[20];
  const float* gc2_b   = (const float*)d_in[21];
  const float* out_W   = (const float*)d_in[22];
  const float* out_b   = (const float*)d_in[23];
  float* out = (float*)d_out;

  float* ws = (float*)d_ws;
  float* lhid  = ws; ws += 524288;
  float* p1    = ws; ws += 262144;
  float* p2    = ws; ws += 262144;
  float* amx   = ws; ws += 2097152;
  float* ssq   = ws; ws += 4096;
  float* Abuf  = ws; ws += 2097152;
  float* t2    = ws; ws += 40960;
  float* Bpkf  = ws; ws += 122880;   // 245760 ushorts (GRU pack)
  float* WbTf  = ws; ws += 262144;   // 2 x 262144 ushorts
  float* t1Tf  = ws; ws += 524288;   // 2 x 524288 ushorts
  if (ws_size < (size_t)(ws - (float*)d_ws) * sizeof(float)) return;
  ushort_t* Bpack  = (ushort_t*)Bpkf;
  ushort_t* WbT_hi = (ushort_t*)WbTf;
  ushort_t* WbT_lo = WbT_hi + 262144;
  ushort_t* t1T_hi = (ushort_t*)t1Tf;
  ushort_t* t1T_lo = t1T_hi + 524288;

  pack_kernel<<<304, 256, 0, stream>>>(gWhh, gWih, Wb, Bpack, WbT_hi, WbT_lo,
                                       ssq, out);
  gru_kernel<<<256, 512, 0, stream>>>(X, Bpack, gbih, gbhh, W1, W2, b1,
                                      lhid, p1, p2);
  conv_t1_kernel<<<512, 128, 0, stream>>>(X, conv_w, conv_b, convl_w, convl_b,
                                          gc1_W, t1T_hi, t1T_lo);
  amx_kernel<<<dim3(16, 16, 8), 256, 0, stream>>>(p1, p2, V, bv, amx, ssq);
  gemm_cA<<<dim3(8, 4, 8), 128, 0, stream>>>(amx, WbT_hi, WbT_lo, adj, wb,
                                             ssq, Abuf);
  gemm_h1t2<<<dim3(16, 8), 256, 0, stream>>>(Abuf, t1T_hi, t1T_lo, gc1_b,
                                             gc2_W, t2);
  spat_readout<<<dim3(32, 8), 256, 0, stream>>>(Abuf, t2, gc2_b, lhid,
                                                out_W, out_b, Y, out);
}

// Round 7
// 263.208 us; speedup vs baseline: 2.2432x; 1.0197x over previous
//
#include <hip/hip_runtime.h>
#include <math.h>

// ---------------- sizes ----------------
#define Bn 8
#define Wn 20
#define Mn 512
#define Fn 16
#define Hn 128
#define HALFn 64
#define Kn 10

typedef __attribute__((ext_vector_type(8))) short short8;
typedef __attribute__((ext_vector_type(4))) float f32x4;
typedef unsigned short ushort_t;

__device__ __forceinline__ float sigmoidf_(float x) {
  return 1.0f / (1.0f + __expf(-x));
}
__device__ __forceinline__ float tanhf_(float x) {
  float xx = fminf(fmaxf(x, -15.f), 15.f);
  float e = __expf(2.f * xx);
  return (e - 1.f) / (e + 1.f);
}
__device__ __forceinline__ float reluf_(float x) { return fmaxf(x, 0.f); }
__device__ __forceinline__ float eluf_(float x) {
  return (x > 0.f) ? x : (__expf(x) - 1.f);
}
__device__ __forceinline__ ushort_t bf16_rne(float v) {
  unsigned u = __float_as_uint(v);
  u += 0x7FFFu + ((u >> 16) & 1u);
  return (ushort_t)(u >> 16);
}
__device__ __forceinline__ float bf16_to_f(ushort_t b) {
  return __uint_as_float(((unsigned)b) << 16);
}

// ---------------- prep: GRU weight pack + Wb transpose/split + zero init ----
__global__ __launch_bounds__(256) void pack_kernel(
    const float* __restrict__ Whh, const float* __restrict__ Wih,
    const float* __restrict__ Wb, ushort_t* __restrict__ Bpack,
    ushort_t* __restrict__ WbT_hi, ushort_t* __restrict__ WbT_lo,
    float* __restrict__ ssq, float* __restrict__ d_out) {
  int tid = threadIdx.x;
  if (blockIdx.x < 240) {
    int idx = blockIdx.x * 256 + tid;   // 24*5*512 = 61440
    if (idx < 4096) ssq[idx] = 0.f;
    if (idx == 0) d_out[0] = 0.f;
    if (idx >= 24 * 5 * 512) return;
    int j = idx & 7;
    int lane = (idx >> 3) & 63;
    int ks = (idx >> 9) % 5;
    int nt = idx / (5 * 512);
    int k = ks * 32 + (lane >> 4) * 8 + j;
    int g = (nt & 7) * 16 + (nt >> 3) * 128 + (lane & 15);
    float val = 0.f;
    if (k < 128) val = Whh[g * 128 + k];
    else if (k < 144) val = Wih[g * 16 + (k - 128)];
    ushort_t hb = bf16_rne(val);
    float lo = val - bf16_to_f(hb);
    Bpack[(((long)nt * 5 + ks) * 2 + 0) * 512 + lane * 8 + j] = hb;
    Bpack[(((long)nt * 5 + ks) * 2 + 1) * 512 + lane * 8 + j] = bf16_rne(lo);
  } else {
    int t = blockIdx.x - 240;           // 0..63
    int k0 = (t >> 3) * 64, j0 = (t & 7) * 64;
    __shared__ float wt[64][65];
    for (int idx = tid; idx < 4096; idx += 256) {
      int r = idx >> 6, c = idx & 63;
      wt[r][c] = Wb[(long)(k0 + r) * 512 + j0 + c];
    }
    __syncthreads();
    for (int idx = tid; idx < 4096; idx += 256) {
      int r = idx >> 6, c = idx & 63;
      float v = wt[c][r];
      ushort_t hb = bf16_rne(v);
      WbT_hi[(long)(j0 + r) * 512 + k0 + c] = hb;
      WbT_lo[(long)(j0 + r) * 512 + k0 + c] = bf16_rne(v - bf16_to_f(hb));
    }
  }
}

// ---------------- GRU: split-bf16 MFMA, double-buffered h (1 barrier/step),
// 7 independent MFMA chains; fused p1/p2 epilogue ----------------
// LDS layout in flat smem_hs: hi(buf) at buf*HSZ, lo(buf) at (2+buf)*HSZ
#define LDK 168
#define HSZ (16 * LDK)
__global__ __launch_bounds__(512, 2) void gru_kernel(
    const float* __restrict__ X, const ushort_t* __restrict__ Bpack,
    const float* __restrict__ bih, const float* __restrict__ bhh,
    const float* __restrict__ W1, const float* __restrict__ W2,
    const float* __restrict__ b1, float* __restrict__ last_hid,
    float* __restrict__ p1, float* __restrict__ p2) {
  const int tid = threadIdx.x;
  const int wave = tid >> 6;
  const int lane = tid & 63;
  const int quad = lane >> 4;
  const int jl = lane & 15;
  const int j0 = wave * 16;
  const int blk = blockIdx.x;
  const int b = blk >> 5;
  const int m0 = (blk & 31) * 16;

  __shared__ __align__(16) ushort_t smem_hs[4 * HSZ];  // hi0,hi1,lo0,lo1

  short8 frR[5][2], frZ[5][2], frN[4][2], frXN[2];
#pragma unroll
  for (int ks = 0; ks < 5; ++ks) {
#pragma unroll
    for (int p = 0; p < 2; ++p) {
      frR[ks][p] = *(const short8*)&Bpack[(((long)(wave) * 5 + ks) * 2 + p) * 512 + lane * 8];
      frZ[ks][p] = *(const short8*)&Bpack[(((long)(8 + wave) * 5 + ks) * 2 + p) * 512 + lane * 8];
    }
  }
#pragma unroll
  for (int ks = 0; ks < 4; ++ks) {
#pragma unroll
    for (int p = 0; p < 2; ++p)
      frN[ks][p] = *(const short8*)&Bpack[(((long)(16 + wave) * 5 + ks) * 2 + p) * 512 + lane * 8];
  }
#pragma unroll
  for (int p = 0; p < 2; ++p)
    frXN[p] = *(const short8*)&Bpack[(((long)(16 + wave) * 5 + 4) * 2 + p) * 512 + lane * 8];

  const float cr  = bih[j0 + jl] + bhh[j0 + jl];
  const float cz  = bih[128 + j0 + jl] + bhh[128 + j0 + jl];
  const float cnx = bih[256 + j0 + jl];
  const float cnh = bhh[256 + j0 + jl];

  for (int i = tid; i < 4 * HSZ; i += 512) smem_hs[i] = 0;

  const float* Xb = X + (long)b * (Wn * Mn * Fn) + (long)m0 * Fn;
  float x0 = 0.f;
  if (tid < 256) x0 = Xb[tid];
  __syncthreads();
  if (tid < 256) {
    int s = tid >> 4, f = tid & 15;
    ushort_t hb = bf16_rne(x0);
    smem_hs[0 * HSZ + s * LDK + 128 + f] = hb;                 // hi buf0
    smem_hs[2 * HSZ + s * LDK + 128 + f] = bf16_rne(x0 - bf16_to_f(hb));  // lo buf0
  }
  __syncthreads();

  float hp[4] = {0.f, 0.f, 0.f, 0.f};

  for (int t = 0; t < Wn; ++t) {
    const int cur = t & 1, nxt = cur ^ 1;
    const int hiC = cur * HSZ, loC = (2 + cur) * HSZ;
    const int hiN = nxt * HSZ, loN = (2 + nxt) * HSZ;
    float xpre = 0.f;
    if (tid < 256 && t < Wn - 1) xpre = Xb[(long)(t + 1) * (Mn * Fn) + tid];

    // 7 independent MFMA chains (split by ks parity) — max depth 9
    f32x4 aR[2], aZ[2], aHN[2], aXN;
    aR[0] = aR[1] = aZ[0] = aZ[1] = aHN[0] = aHN[1] = aXN = (f32x4){0.f, 0.f, 0.f, 0.f};
#pragma unroll
    for (int ks = 0; ks < 5; ++ks) {
      const int p = ks & 1;
      short8 ah = *(const short8*)&smem_hs[hiC + jl * LDK + ks * 32 + quad * 8];
      short8 al = *(const short8*)&smem_hs[loC + jl * LDK + ks * 32 + quad * 8];
      aR[p] = __builtin_amdgcn_mfma_f32_16x16x32_bf16(ah, frR[ks][0], aR[p], 0, 0, 0);
      aR[p] = __builtin_amdgcn_mfma_f32_16x16x32_bf16(ah, frR[ks][1], aR[p], 0, 0, 0);
      aR[p] = __builtin_amdgcn_mfma_f32_16x16x32_bf16(al, frR[ks][0], aR[p], 0, 0, 0);
      aZ[p] = __builtin_amdgcn_mfma_f32_16x16x32_bf16(ah, frZ[ks][0], aZ[p], 0, 0, 0);
      aZ[p] = __builtin_amdgcn_mfma_f32_16x16x32_bf16(ah, frZ[ks][1], aZ[p], 0, 0, 0);
      aZ[p] = __builtin_amdgcn_mfma_f32_16x16x32_bf16(al, frZ[ks][0], aZ[p], 0, 0, 0);
      if (ks < 4) {
        aHN[p] = __builtin_amdgcn_mfma_f32_16x16x32_bf16(ah, frN[ks][0], aHN[p], 0, 0, 0);
        aHN[p] = __builtin_amdgcn_mfma_f32_16x16x32_bf16(ah, frN[ks][1], aHN[p], 0, 0, 0);
        aHN[p] = __builtin_amdgcn_mfma_f32_16x16x32_bf16(al, frN[ks][0], aHN[p], 0, 0, 0);
      } else {
        aXN = __builtin_amdgcn_mfma_f32_16x16x32_bf16(ah, frXN[0], aXN, 0, 0, 0);
        aXN = __builtin_amdgcn_mfma_f32_16x16x32_bf16(ah, frXN[1], aXN, 0, 0, 0);
        aXN = __builtin_amdgcn_mfma_f32_16x16x32_bf16(al, frXN[0], aXN, 0, 0, 0);
      }
    }

    // gate math; write h(t+1) into the NEXT buffer (no read/write conflict)
#pragma unroll
    for (int reg = 0; reg < 4; ++reg) {
      float r = sigmoidf_(aR[0][reg] + aR[1][reg] + cr);
      float z = sigmoidf_(aZ[0][reg] + aZ[1][reg] + cz);
      float n = tanhf_(aXN[reg] + cnx + r * (aHN[0][reg] + aHN[1][reg] + cnh));
      float h = (1.f - z) * n + z * hp[reg];
      hp[reg] = h;
      int s = quad * 4 + reg;
      ushort_t hb = bf16_rne(h);
      smem_hs[hiN + s * LDK + j0 + jl] = hb;
      smem_hs[loN + s * LDK + j0 + jl] = bf16_rne(h - bf16_to_f(hb));
    }
    if (tid < 256 && t < Wn - 1) {
      int s = tid >> 4, f = tid & 15;
      ushort_t hb = bf16_rne(xpre);
      smem_hs[hiN + s * LDK + 128 + f] = hb;
      smem_hs[loN + s * LDK + 128 + f] = bf16_rne(xpre - bf16_to_f(hb));
    }
    __syncthreads();   // single barrier per step
  }

  float* hs_f = (float*)smem_hs;          // 16 x 132 floats
#pragma unroll
  for (int reg = 0; reg < 4; ++reg) {
    int s = quad * 4 + reg;
    float h = hp[reg];
    last_hid[(long)(blk * 16 + s) * Hn + j0 + jl] = h;
    hs_f[s * 132 + j0 + jl] = h;
  }
  __syncthreads();
  {
    int k = tid & 63;
    int part = (tid >> 6) & 1;
    int sg = tid >> 7;
    const float* Wp = part ? W2 : W1;
    float a[4];
    float init = part ? 0.f : b1[k];
    a[0] = a[1] = a[2] = a[3] = init;
    for (int h = 0; h < 128; h += 4) {
      float4 w = *(const float4*)&Wp[k * 128 + h];
#pragma unroll
      for (int rr = 0; rr < 4; ++rr) {
        float4 q = *(const float4*)&hs_f[(sg * 4 + rr) * 132 + h];
        a[rr] += q.x * w.x + q.y * w.y + q.z * w.z + q.w * w.w;
      }
    }
    float* outp = part ? p2 : p1;
#pragma unroll
    for (int rr = 0; rr < 4; ++rr)
      outp[(long)(blk * 16 + sg * 4 + rr) * 64 + k] = a[rr];
  }
}

// ---------------- fused conv + t1; t1 emitted as bf16 hi/lo TRANSPOSED [h][m] ----
__global__ __launch_bounds__(128) void conv_t1_kernel(
    const float* __restrict__ X, const float* __restrict__ conv_w,
    const float* __restrict__ conv_b, const float* __restrict__ convl_w,
    const float* __restrict__ convl_b, const float* __restrict__ gc1_W,
    ushort_t* __restrict__ t1T_hi, ushort_t* __restrict__ t1T_lo) {
  int tid = threadIdx.x;
  int n0 = blockIdx.x * 8;
  int b = n0 >> 9, m0 = n0 & 511;
  __shared__ float xs[8][16][20];
  __shared__ float cw[3200];
  __shared__ float clw[1600];
  __shared__ float rs[8][32];
  for (int idx = tid; idx < 3200; idx += 128) cw[idx] = conv_w[idx];
  for (int idx = tid; idx < 1600; idx += 128) clw[idx] = convl_w[idx];
  for (int w = 0; w < 20; ++w)
    xs[tid >> 4][tid & 15][w] = X[((long)(b * 20 + w) * 512 + m0) * 16 + tid];
  __syncthreads();
  if (tid < 80) {
    int s = tid / 10, k = tid % 10;
    float a0 = conv_b[k];
    float l0 = convl_b[k], l1 = convl_b[k];
    for (int f = 0; f < 16; ++f) {
#pragma unroll
      for (int w = 0; w < 20; ++w) a0 = fmaf(xs[s][f][w], cw[k * 320 + f * 20 + w], a0);
#pragma unroll
      for (int q = 0; q < 10; ++q) {
        float wv = clw[k * 160 + f * 10 + q];
        l0 = fmaf(xs[s][f][2 * q], wv, l0);
        l1 = fmaf(xs[s][f][2 * q + 1], wv, l1);
      }
    }
    rs[s][k * 3 + 0] = reluf_(a0);
    rs[s][k * 3 + 1] = reluf_(l0);
    rs[s][k * 3 + 2] = reluf_(l1);
  }
  __syncthreads();
  float w[30];
#pragma unroll
  for (int q = 0; q < 30; ++q) w[q] = gc1_W[q * 128 + tid];
  long base = ((long)b * 128 + tid) * 512 + m0;
#pragma unroll
  for (int s = 0; s < 8; ++s) {
    float a = 0.f;
#pragma unroll
    for (int q = 0; q < 30; ++q) a = fmaf(rs[s][q], w[q], a);
    ushort_t hb = bf16_rne(a);
    t1T_hi[base + s] = hb;
    t1T_lo[base + s] = bf16_rne(a - bf16_to_f(hb));
  }
}

// ---------------- a_mx raw (32x32 tile) + fused column sum-of-squares ----------------
__global__ __launch_bounds__(256) void amx_kernel(
    const float* __restrict__ p1, const float* __restrict__ p2,
    const float* __restrict__ V, const float* __restrict__ bv,
    float* __restrict__ amx, float* __restrict__ ssq) {
  int tid = threadIdx.x;
  int j0 = blockIdx.x * 32, i0 = blockIdx.y * 32, bz = blockIdx.z;
  __shared__ float p1s[32][68];
  __shared__ float p2s[32][68];
  __shared__ float Vs[64];
  __shared__ float cred[16][33];
  if (tid < 64) Vs[tid] = V[tid];
  {
    int rr = tid >> 3, c0 = (tid & 7) * 8;
    *(float4*)&p1s[rr][c0]     = *(const float4*)&p1[(long)(bz * 512 + j0 + rr) * 64 + c0];
    *(float4*)&p1s[rr][c0 + 4] = *(const float4*)&p1[(long)(bz * 512 + j0 + rr) * 64 + c0 + 4];
    *(float4*)&p2s[rr][c0]     = *(const float4*)&p2[(long)(bz * 512 + i0 + rr) * 64 + c0];
    *(float4*)&p2s[rr][c0 + 4] = *(const float4*)&p2[(long)(bz * 512 + i0 + rr) * 64 + c0 + 4];
  }
  __syncthreads();
  int r0 = tid >> 4, c0 = tid & 15;
  float acc[2][2] = {{0.f, 0.f}, {0.f, 0.f}};
  for (int k = 0; k < 64; ++k) {
    float vj0 = p1s[c0][k], vj1 = p1s[c0 + 16][k];
    float vi0 = p2s[r0][k], vi1 = p2s[r0 + 16][k];
    float vk = Vs[k];
    acc[0][0] = fmaf(eluf_(vj0 + vi0), vk, acc[0][0]);
    acc[0][1] = fmaf(eluf_(vj1 + vi0), vk, acc[0][1]);
    acc[1][0] = fmaf(eluf_(vj0 + vi1), vk, acc[1][0]);
    acc[1][1] = fmaf(eluf_(vj1 + vi1), vk, acc[1][1]);
  }
  float bvv = bv[0];
  float s2[2] = {0.f, 0.f};
#pragma unroll
  for (int a = 0; a < 2; ++a)
#pragma unroll
    for (int c = 0; c < 2; ++c) {
      float v = acc[a][c] + bvv;
      amx[((long)(bz * 512 + i0 + r0 + a * 16)) * 512 + j0 + c0 + c * 16] = v;
      s2[c] += v * v;
    }
  cred[r0][c0] = s2[0];
  cred[r0][c0 + 16] = s2[1];
  __syncthreads();
  if (tid < 32) {
    float s = 0.f;
#pragma unroll
    for (int p = 0; p < 16; ++p) s += cred[p][tid];
    atomicAdd(&ssq[bz * 512 + j0 + tid], s);
  }
}

// ---- gemm_cA via split-bf16 MFMA ----
#define CPK 40
__global__ __launch_bounds__(128, 2) void gemm_cA(
    const float* __restrict__ amx, const ushort_t* __restrict__ WbT_hi,
    const ushort_t* __restrict__ WbT_lo, const float* __restrict__ adj,
    const float* __restrict__ wb, const float* __restrict__ ssq,
    float* __restrict__ A) {
  const int bz = blockIdx.z;
  const int i0 = blockIdx.y * 128;
  const int j0 = blockIdx.x * 64;
  const int tid = threadIdx.x;
  const int wave = tid >> 6;
  const int lane = tid & 63;
  const int quad = lane >> 4, jl = lane & 15;

  __shared__ __align__(16) ushort_t Ahi[128][CPK];
  __shared__ __align__(16) ushort_t Alo[128][CPK];
  __shared__ __align__(16) ushort_t Bhi[64][CPK];
  __shared__ __align__(16) ushort_t Blo[64][CPK];
  __shared__ float rs_s[512];

  const float* Abase = amx + (long)bz * 262144;
  const float* sb = ssq + bz * 512;
  for (int i = tid; i < 512; i += 128)
    rs_s[i] = 1.f / fmaxf(sqrtf(sb[i]), 1e-12f);

  f32x4 acc[4][4];
#pragma unroll
  for (int a = 0; a < 4; ++a)
#pragma unroll
    for (int c = 0; c < 4; ++c) acc[a][c] = (f32x4){0.f, 0.f, 0.f, 0.f};

  for (int kk0 = 0; kk0 < 512; kk0 += 32) {
    __syncthreads();
#pragma unroll
    for (int l = 0; l < 8; ++l) {
      int e = l * 512 + tid * 4;
      int r = e >> 5, kq = e & 31;
      float4 v = *(const float4*)&Abase[(long)(i0 + r) * 512 + kk0 + kq];
      float4 sc = *(const float4*)&rs_s[kk0 + kq];
      float vv[4] = {v.x * sc.x, v.y * sc.y, v.z * sc.z, v.w * sc.w};
#pragma unroll
      for (int q = 0; q < 4; ++q) {
        ushort_t hb = bf16_rne(vv[q]);
        Ahi[r][kq + q] = hb;
        Alo[r][kq + q] = bf16_rne(vv[q] - bf16_to_f(hb));
      }
    }
#pragma unroll
    for (int l = 0; l < 2; ++l) {
      int e = l * 1024 + tid * 8;
      int r = e >> 5, kc = e & 31;
      *(uint4*)&Bhi[r][kc] = *(const uint4*)&WbT_hi[(long)(j0 + r) * 512 + kk0 + kc];
      *(uint4*)&Blo[r][kc] = *(const uint4*)&WbT_lo[(long)(j0 + r) * 512 + kk0 + kc];
    }
    __syncthreads();
    short8 ah[4], al[4], bh[4], bl[4];
#pragma unroll
    for (int tm = 0; tm < 4; ++tm) {
      ah[tm] = *(const short8*)&Ahi[wave * 64 + tm * 16 + jl][quad * 8];
      al[tm] = *(const short8*)&Alo[wave * 64 + tm * 16 + jl][quad * 8];
    }
#pragma unroll
    for (int tn = 0; tn < 4; ++tn) {
      bh[tn] = *(const short8*)&Bhi[tn * 16 + jl][quad * 8];
      bl[tn] = *(const short8*)&Blo[tn * 16 + jl][quad * 8];
    }
#pragma unroll
    for (int tm = 0; tm < 4; ++tm)
#pragma unroll
      for (int tn = 0; tn < 4; ++tn) {
        acc[tm][tn] = __builtin_amdgcn_mfma_f32_16x16x32_bf16(ah[tm], bh[tn], acc[tm][tn], 0, 0, 0);
        acc[tm][tn] = __builtin_amdgcn_mfma_f32_16x16x32_bf16(ah[tm], bl[tn], acc[tm][tn], 0, 0, 0);
        acc[tm][tn] = __builtin_amdgcn_mfma_f32_16x16x32_bf16(al[tm], bh[tn], acc[tm][tn], 0, 0, 0);
      }
  }

  const float wbv = wb[0];
#pragma unroll
  for (int tn = 0; tn < 4; ++tn) {
    int j = j0 + tn * 16 + jl;
    float sj = rs_s[j];
#pragma unroll
    for (int tm = 0; tm < 4; ++tm) {
#pragma unroll
      for (int reg = 0; reg < 4; ++reg) {
        int i = i0 + wave * 64 + tm * 16 + quad * 4 + reg;
        long ofs = (long)bz * 262144 + (long)i * 512 + j;
        float c = sigmoidf_(acc[tm][tn][reg] + wbv);
        float am = Abase[(long)i * 512 + j] * sj;
        float ad = adj[(long)i * 512 + j];
        A[ofs] = ad * c + am * (1.f - c);
      }
    }
  }
}

// ---------------- gemm_h1 (BM=16, 256 blocks) + fused t2 = h1 @ gc2_W ----------------
__global__ __launch_bounds__(256, 2) void gemm_h1t2(
    const float* __restrict__ A, const ushort_t* __restrict__ t1T_hi,
    const ushort_t* __restrict__ t1T_lo, const float* __restrict__ gc1_b,
    const float* __restrict__ gc2_W, float* __restrict__ t2) {
  const int bz = blockIdx.y;
  const int i0 = blockIdx.x * 16;
  const int tid = threadIdx.x;
  const int wave = tid >> 6;
  const int lane = tid & 63;
  const int quad = lane >> 4, jl = lane & 15;

  __shared__ __align__(16) ushort_t Ahi[16][CPK];
  __shared__ __align__(16) ushort_t Alo[16][CPK];
  __shared__ __align__(16) ushort_t Bhi[128][CPK];
  __shared__ __align__(16) ushort_t Blo[128][CPK];
  __shared__ float h1s[16][132];
  __shared__ float gw[1280];

  const float* Ab = A + (long)bz * 262144;
  for (int idx = tid; idx < 1280; idx += 256) gw[idx] = gc2_W[idx];

  f32x4 acc[2];
  acc[0] = acc[1] = (f32x4){0.f, 0.f, 0.f, 0.f};

  for (int kk0 = 0; kk0 < 512; kk0 += 32) {
    __syncthreads();
    {
      int e = tid * 2;
      int r = e >> 5, kq = e & 31;
      float2 v = *(const float2*)&Ab[(long)(i0 + r) * 512 + kk0 + kq];
      ushort_t hb0 = bf16_rne(v.x);
      Ahi[r][kq] = hb0;
      Alo[r][kq] = bf16_rne(v.x - bf16_to_f(hb0));
      ushort_t hb1 = bf16_rne(v.y);
      Ahi[r][kq + 1] = hb1;
      Alo[r][kq + 1] = bf16_rne(v.y - bf16_to_f(hb1));
    }
#pragma unroll
    for (int l = 0; l < 2; ++l) {
      int e = l * 2048 + tid * 8;
      int r = e >> 5, kc = e & 31;
      *(uint4*)&Bhi[r][kc] = *(const uint4*)&t1T_hi[((long)bz * 128 + r) * 512 + kk0 + kc];
      *(uint4*)&Blo[r][kc] = *(const uint4*)&t1T_lo[((long)bz * 128 + r) * 512 + kk0 + kc];
    }
    __syncthreads();
    short8 ah = *(const short8*)&Ahi[jl][quad * 8];
    short8 al = *(const short8*)&Alo[jl][quad * 8];
    short8 bh[2], bl[2];
#pragma unroll
    for (int tn = 0; tn < 2; ++tn) {
      bh[tn] = *(const short8*)&Bhi[wave * 32 + tn * 16 + jl][quad * 8];
      bl[tn] = *(const short8*)&Blo[wave * 32 + tn * 16 + jl][quad * 8];
    }
#pragma unroll
    for (int tn = 0; tn < 2; ++tn) {
      acc[tn] = __builtin_amdgcn_mfma_f32_16x16x32_bf16(ah, bh[tn], acc[tn], 0, 0, 0);
      acc[tn] = __builtin_amdgcn_mfma_f32_16x16x32_bf16(ah, bl[tn], acc[tn], 0, 0, 0);
      acc[tn] = __builtin_amdgcn_mfma_f32_16x16x32_bf16(al, bh[tn], acc[tn], 0, 0, 0);
    }
  }
  __syncthreads();
#pragma unroll
  for (int tn = 0; tn < 2; ++tn) {
    int n = wave * 32 + tn * 16 + jl;
    float bb = gc1_b[n];
#pragma unroll
    for (int reg = 0; reg < 4; ++reg) {
      int r = quad * 4 + reg;
      h1s[r][n] = reluf_(acc[tn][reg] + bb);
    }
  }
  __syncthreads();
  if (tid < 160) {
    int r = tid / 10, c = tid % 10;
    float a = 0.f;
#pragma unroll 4
    for (int k = 0; k < 128; ++k) a = fmaf(h1s[r][k], gw[k * 10 + c], a);
    t2[((long)bz * 512 + i0 + r) * 10 + c] = a;
  }
}

// ---------------- out_spatial = relu(A @ t2 + b2) fused with readout + BCE ----------
__global__ __launch_bounds__(256) void spat_readout(
    const float* __restrict__ A, const float* __restrict__ t2,
    const float* __restrict__ gc2_b, const float* __restrict__ last_hid,
    const float* __restrict__ out_W, const float* __restrict__ out_b,
    const float* __restrict__ Y, float* __restrict__ d_out) {
  int tid = threadIdx.x;
  int bz = blockIdx.y;
  int i0 = blockIdx.x * 16;
  __shared__ float t2s[5120];
  __shared__ float wS[138];
  __shared__ float osps[16][12];
  for (int idx = tid; idx < 5120; idx += 256) t2s[idx] = t2[(long)bz * 5120 + idx];
  for (int idx = tid; idx < 138; idx += 256) wS[idx] = out_W[idx];
  __syncthreads();
  int r = tid >> 4, sk = tid & 15;
  const float* Arow = A + (long)bz * 262144 + (long)(i0 + r) * 512;
  float acc[10] = {0, 0, 0, 0, 0, 0, 0, 0, 0, 0};
  for (int k = sk; k < 512; k += 16) {
    float av = Arow[k];
    const float* tp = &t2s[k * 10];
#pragma unroll
    for (int c = 0; c < 10; ++c) acc[c] = fmaf(av, tp[c], acc[c]);
  }
#pragma unroll
  for (int off = 8; off; off >>= 1)
#pragma unroll
    for (int c = 0; c < 10; ++c) acc[c] += __shfl_xor(acc[c], off);
  if (sk == 0) {
#pragma unroll
    for (int c = 0; c < 10; ++c) osps[r][c] = reluf_(acc[c] + gc2_b[c]);
  }
  __syncthreads();
  float l = 0.f;
  if (tid < 16) {
    int gid = bz * 512 + i0 + tid;
    float y = out_b[0];
#pragma unroll
    for (int k = 0; k < 10; ++k) y = fmaf(osps[tid][k], wS[k], y);
    const float* hp = &last_hid[(long)gid * 128];
    for (int h = 0; h < 128; h += 4) {
      float4 hv = *(const float4*)&hp[h];
      y = fmaf(hv.x, wS[10 + h + 0], y);
      y = fmaf(hv.y, wS[10 + h + 1], y);
      y = fmaf(hv.z, wS[10 + h + 2], y);
      y = fmaf(hv.w, wS[10 + h + 3], y);
    }
    d_out[1 + gid] = sigmoidf_(y);
    l = fmaxf(y, 0.f) + log1pf(__expf(-fabsf(y))) - Y[gid] * y;
  }
  if (tid < 64) {
#pragma unroll
    for (int off = 8; off; off >>= 1) l += __shfl_down(l, off);
    if (tid == 0) atomicAdd(d_out, l * (1.0f / 4096.f));
  }
}

// ---------------- launcher ----------------
extern "C" void kernel_launch(void* const* d_in, const int* in_sizes, int n_in,
                              void* d_out, int out_size, void* d_ws, size_t ws_size,
                              hipStream_t stream) {
  const float* X       = (const float*)d_in[0];
  const float* Y       = (const float*)d_in[1];
  const float* adj     = (const float*)d_in[2];
  const float* V       = (const float*)d_in[3];
  const float* bv      = (const float*)d_in[4];
  const float* W1      = (const float*)d_in[5];
  const float* b1      = (const float*)d_in[6];
  const float* W2      = (const float*)d_in[7];
  const float* Wb      = (const float*)d_in[8];
  const float* wb      = (const float*)d_in[9];
  const float* conv_w  = (const float*)d_in[10];
  const float* conv_b  = (const float*)d_in[11];
  const float* convl_w = (const float*)d_in[12];
  const float* convl_b = (const float*)d_in[13];
  const float* gWih    = (const float*)d_in[14];
  const float* gWhh    = (const float*)d_in[15];
  const float* gbih    = (const float*)d_in[16];
  const float* gbhh    = (const float*)d_in[17];
  const float* gc1_W   = (const float*)d_in[18];
  const float* gc1_b   = (const float*)d_in[19];
  const float* gc2_W   = (const float*)d_in[20];
  const float* gc2_b   = (const float*)d_in[21];
  const float* out_W   = (const float*)d_in[22];
  const float* out_b   = (const float*)d_in[23];
  float* out = (float*)d_out;

  float* ws = (float*)d_ws;
  float* lhid  = ws; ws += 524288;
  float* p1    = ws; ws += 262144;
  float* p2    = ws; ws += 262144;
  float* amx   = ws; ws += 2097152;
  float* ssq   = ws; ws += 4096;
  float* Abuf  = ws; ws += 2097152;
  float* t2    = ws; ws += 40960;
  float* Bpkf  = ws; ws += 122880;   // 245760 ushorts (GRU pack)
  float* WbTf  = ws; ws += 262144;   // 2 x 262144 ushorts
  float* t1Tf  = ws; ws += 524288;   // 2 x 524288 ushorts
  if (ws_size < (size_t)(ws - (float*)d_ws) * sizeof(float)) return;
  ushort_t* Bpack  = (ushort_t*)Bpkf;
  ushort_t* WbT_hi = (ushort_t*)WbTf;
  ushort_t* WbT_lo = WbT_hi + 262144;
  ushort_t* t1T_hi = (ushort_t*)t1Tf;
  ushort_t* t1T_lo = t1T_hi + 524288;

  pack_kernel<<<304, 256, 0, stream>>>(gWhh, gWih, Wb, Bpack, WbT_hi, WbT_lo,
                                       ssq, out);
  gru_kernel<<<256, 512, 0, stream>>>(X, Bpack, gbih, gbhh, W1, W2, b1,
                                      lhid, p1, p2);
  conv_t1_kernel<<<512, 128, 0, stream>>>(X, conv_w, conv_b, convl_w, convl_b,
                                          gc1_W, t1T_hi, t1T_lo);
  amx_kernel<<<dim3(16, 16, 8), 256, 0, stream>>>(p1, p2, V, bv, amx, ssq);
  gemm_cA<<<dim3(8, 4, 8), 128, 0, stream>>>(amx, WbT_hi, WbT_lo, adj, wb,
                                             ssq, Abuf);
  gemm_h1t2<<<dim3(32, 8), 256, 0, stream>>>(Abuf, t1T_hi, t1T_lo, gc1_b,
                                             gc2_W, t2);
  spat_readout<<<dim3(32, 8), 256, 0, stream>>>(Abuf, t2, gc2_b, lhid,
                                                out_W, out_b, Y, out);
}